// Round 7
// baseline (372.524 us; speedup 1.0000x reference)
//
#include <hip/hip_runtime.h>
#include <stdint.h>

#define NB 2
#define SL 4096
#define NH 16
#define HD 128
#define DS 256
#define CK 256
#define NCH 16
#define NSQ 4
#define DI 2048

typedef unsigned short u16;
typedef unsigned int u32;
typedef __attribute__((ext_vector_type(8))) __bf16 bf16x8;
typedef __attribute__((ext_vector_type(4))) float f32x4;

__device__ __forceinline__ int tor(int dir, int t) { return dir ? (SL - 1 - t) : t; }

__device__ __forceinline__ u16 f2bf(float f) {
  u32 u = __float_as_uint(f);
  u = u + 0x7fffu + ((u >> 16) & 1u);   // RNE
  return (u16)(u >> 16);
}
__device__ __forceinline__ float bf2f(u16 s) {
  return __uint_as_float(((u32)s) << 16);
}

__device__ __forceinline__ void gl_lds16(const u16* g, u16* l) {
  __builtin_amdgcn_global_load_lds((const __attribute__((address_space(1))) u32*)g,
                                   (__attribute__((address_space(3))) u32*)l, 16, 0, 0);
}

__device__ __forceinline__ void cfence() { asm volatile("" ::: "memory"); }
__device__ __forceinline__ void spin() { __builtin_amdgcn_sched_barrier(0); }

// Stage a 32-row slice of a tile (row stride 256 elems in global) into LDS rows
// [w*32, w*32+32) of a [*][32] buffer, 16B chunks XOR-swizzled by ((row>>1)&3).
// 2 gl_lds per thread.
__device__ __forceinline__ void stage_tile(const u16* __restrict__ src, u16* lds,
                                           int lane, int w, int k0) {
  int sgrow = lane >> 2, sc = lane & 3;
  int r0 = w << 5;
  int ra = r0 + sgrow, rb = ra + 16;
  int kqa = (sc ^ ((ra >> 1) & 3)) << 3;
  int kqb = (sc ^ ((rb >> 1) & 3)) << 3;
  gl_lds16(src + (size_t)ra * 256 + k0 + kqa, lds + r0 * 32);
  gl_lds16(src + (size_t)rb * 256 + k0 + kqb, lds + (r0 + 16) * 32);
}

// 8 waves (512 threads) stage a 128x32 tile: wave w stages rows [w*16, w*16+16),
// 1 gl_lds per thread. Same swizzle as stage_tile.
__device__ __forceinline__ void stage_half(const u16* __restrict__ src, u16* lds,
                                           int lane, int w, int k0) {
  int row = (w << 4) + (lane >> 2);
  int sc = lane & 3;
  int kq = (sc ^ ((row >> 1) & 3)) << 3;
  gl_lds16(src + (size_t)row * 256 + k0 + kq, lds + (w << 4) * 32);
}

__device__ __forceinline__ bf16x8 frag(const u16* lds, int base_row, int m, int quad) {
  int row = base_row + m;
  return *(const bf16x8*)&lds[row * 32 + ((quad ^ ((row >> 1) & 3)) << 3)];
}

__device__ __forceinline__ void mfma16(const u16* As, const u16* Bs, int wi, int wp,
                                       int m, int quad, f32x4 acc[4][4]) {
  bf16x8 af[4], bv[4];
#pragma unroll
  for (int r = 0; r < 4; ++r) af[r] = frag(As, wi + (r << 4), m, quad);
#pragma unroll
  for (int c = 0; c < 4; ++c) bv[c] = frag(Bs, wp + (c << 4), m, quad);
#pragma unroll
  for (int r = 0; r < 4; ++r)
#pragma unroll
    for (int c = 0; c < 4; ++c)
      acc[r][c] = __builtin_amdgcn_mfma_f32_16x16x32_bf16(af[r], bv[c], acc[r][c], 0, 0, 0);
}

// ---- prep: softplus(dt), per-chunk cumsum of dA -----------------------------
__global__ __launch_bounds__(256) void kprep(const float* __restrict__ dt,
                                             const float* __restrict__ A_log,
                                             float* __restrict__ csb,
                                             float* __restrict__ dtvb,
                                             float* __restrict__ cdecb) {
  int blk = blockIdx.x;                 // sj*16 + h
  int h = blk & 15, sj = blk >> 4;
  int s = sj >> 4, j = sj & 15;
  int b = s & 1, dir = s >> 1;
  int i = threadIdx.x;
  int to = tor(dir, j * CK + i);
  __shared__ float sbuf[CK];
  float a = -expf(A_log[h]);
  float raw = dt[((size_t)(b * SL + to)) * (2 * NH) + dir * NH + h];
  float sp = (raw > 20.f) ? raw : log1pf(expf(raw));
  sbuf[i] = sp * a;
  __syncthreads();
  for (int off = 1; off < CK; off <<= 1) {
    float v = (i >= off) ? sbuf[i - off] : 0.f;
    __syncthreads();
    sbuf[i] += v;
    __syncthreads();
  }
  float csv = sbuf[i];
  size_t base = ((size_t)sj * NH + h) * CK;
  csb[base + i] = csv;
  dtvb[base + i] = sp;
  if (i == CK - 1) cdecb[sj * NH + h] = expf(csv);
}

// ---- cast BC -> bf16 B/C with flip applied: [s][t][n], vectorized ------------
__global__ __launch_bounds__(256) void kcast(const float* __restrict__ BC,
                                             u16* __restrict__ Bbf,
                                             u16* __restrict__ Cbf) {
  int blk = blockIdx.x;                 // s*(SL/8) + tg
  int s = blk >> 9, tg = blk & 511;
  int b = s & 1, dir = s >> 1;
  int tid = threadIdx.x;
  int rr = tid >> 6, q = tid & 63;      // 4 rows per iter, 64 threads per row
  int isC = q >> 5, qq = q & 31;
#pragma unroll
  for (int it = 0; it < 2; ++it) {
    int t = tg * 8 + it * 4 + rr;
    int tsrc = tor(dir, t);
    const float* src = BC + ((size_t)(b * SL + tsrc)) * (2 * DS) + q * 8;
    float4 v0 = ((const float4*)src)[0];
    float4 v1 = ((const float4*)src)[1];
    uint4 wv;
    wv.x = (u32)f2bf(v0.x) | ((u32)f2bf(v0.y) << 16);
    wv.y = (u32)f2bf(v0.z) | ((u32)f2bf(v0.w) << 16);
    wv.z = (u32)f2bf(v1.x) | ((u32)f2bf(v1.y) << 16);
    wv.w = (u32)f2bf(v1.z) | ((u32)f2bf(v1.w) << 16);
    u16* dstb = (isC ? Cbf : Bbf) + ((size_t)s * SL + t) * DS + qq * 8;
    *(uint4*)dstb = wv;
  }
}

// ---- transpose B within chunk: BbfT[sj][n][k], one k-slice per block ---------
__global__ __launch_bounds__(256) void ktransB(const u16* __restrict__ Bbf,
                                               u16* __restrict__ BbfT) {
  int blk = blockIdx.x;                 // sj*4 + kslice
  int kslice = blk & 3, sj = blk >> 2;
  int k0 = kslice << 6;
  int s = sj >> 4, j = sj & 15;
  __shared__ u16 T[64 * 264];
  int tid = threadIdx.x;
  const u16* src = Bbf + ((size_t)s * SL + j * CK) * DS;
  u16* dst = BbfT + (size_t)sj * DS * CK;
  int kr = tid >> 2, part = (tid & 3) * 64;
  {
    const uint4* gs = (const uint4*)(src + (size_t)(k0 + kr) * DS + part);
    uint4* tb = (uint4*)&T[kr * 264 + part];
#pragma unroll
    for (int q = 0; q < 8; ++q) tb[q] = gs[q];
  }
  __syncthreads();
  int n = tid;
  u16 col[64];
#pragma unroll
  for (int kq = 0; kq < 64; ++kq) col[kq] = T[kq * 264 + n];
  uint4* ds_ = (uint4*)(dst + (size_t)n * CK + k0);
#pragma unroll
  for (int q = 0; q < 8; ++q) {
    uint4 wv;
    wv.x = (u32)col[q * 8 + 0] | ((u32)col[q * 8 + 1] << 16);
    wv.y = (u32)col[q * 8 + 2] | ((u32)col[q * 8 + 3] << 16);
    wv.z = (u32)col[q * 8 + 4] | ((u32)col[q * 8 + 5] << 16);
    wv.w = (u32)col[q * 8 + 6] | ((u32)col[q * 8 + 7] << 16);
    ds_[q] = wv;
  }
}

// ---- xsT[inst][p][k] = bf16( x[t(k)][h*128+p] * e^{-cs_k} * dt_k ) ----------
__global__ __launch_bounds__(256) void kxsT(const float* __restrict__ xg,
                                            const float* __restrict__ csb,
                                            const float* __restrict__ dtvb,
                                            u16* __restrict__ xsT) {
  int inst = blockIdx.x;                // ((s*16+j)*16+h)
  int h = inst & 15, sj = inst >> 4;
  int s = sj >> 4, j = sj & 15;
  int b = s & 1, dir = s >> 1;
  int tid = threadIdx.x;
  __shared__ u16 Ls[128 * 40];          // [p][kk], stride 40
  size_t cbase = ((size_t)sj * NH + h) * CK;
  u16* dst = xsT + (size_t)inst * (128 * 256);
  int kk = tid >> 3;
  int pg = (tid & 7) * 16;
  int p2 = tid >> 1, half = tid & 1;
  for (int k0 = 0; k0 < CK; k0 += 32) {
    int kglob = k0 + kk;
    float sc_ = expf(-csb[cbase + kglob]) * dtvb[cbase + kglob];
    int t = tor(dir, j * CK + kglob);
    const float* src = xg + ((size_t)(b * SL + t)) * DI + h * HD + pg;
    float4 v0 = ((const float4*)src)[0];
    float4 v1 = ((const float4*)src)[1];
    float4 v2 = ((const float4*)src)[2];
    float4 v3 = ((const float4*)src)[3];
    float vv[16] = {v0.x, v0.y, v0.z, v0.w, v1.x, v1.y, v1.z, v1.w,
                    v2.x, v2.y, v2.z, v2.w, v3.x, v3.y, v3.z, v3.w};
    __syncthreads();
#pragma unroll
    for (int q = 0; q < 16; ++q) Ls[(pg + q) * 40 + kk] = f2bf(vv[q] * sc_);
    __syncthreads();
    uint4 w0 = *(const uint4*)&Ls[p2 * 40 + half * 16];
    uint4 w1 = *(const uint4*)&Ls[p2 * 40 + half * 16 + 8];
    *(uint4*)&dst[(size_t)p2 * 256 + k0 + half * 16] = w0;
    *(uint4*)&dst[(size_t)p2 * 256 + k0 + half * 16 + 8] = w1;
  }
}

// ---- CBm[sj][i][k] = bf16( sum_n C[i,n]*B[k,n] ), masked k<=i ---------------
// Counted-vmcnt double-buffered pipeline + XCD swizzle + setprio.
__global__ __launch_bounds__(256) void kcb(const u16* __restrict__ Cbf,
                                           const u16* __restrict__ Bbf,
                                           u16* __restrict__ CBm) {
  int bid = blockIdx.x;                 // 192 = 8 XCD * 24
  int g = ((bid & 7) * 24) + (bid >> 3);
  int tri = g % 3;                      // 0:(0,0) 1:(1,0) 2:(1,1)
  int sj = g / 3;
  int it0 = tri ? 128 : 0;
  int kt0 = (tri == 2) ? 128 : 0;
  int s = sj >> 4, j = sj & 15;
  __shared__ u16 As[2][128 * 32];
  __shared__ u16 Bs[2][128 * 32];
  int tid = threadIdx.x;
  int w = tid >> 6, lane = tid & 63;
  int wi = (w >> 1) << 6, wp = (w & 1) << 6;
  int m = lane & 15, quad = lane >> 4;
  const u16* Ab = Cbf + ((size_t)s * SL + j * CK + it0) * DS;
  const u16* Bb = Bbf + ((size_t)s * SL + j * CK + kt0) * DS;
  f32x4 zini = {0.f, 0.f, 0.f, 0.f};
  f32x4 acc[4][4];
#pragma unroll
  for (int r = 0; r < 4; ++r)
#pragma unroll
    for (int c = 0; c < 4; ++c) acc[r][c] = zini;
  stage_tile(Ab, As[0], lane, w, 0);
  stage_tile(Bb, Bs[0], lane, w, 0);
  int cur = 0;
  for (int ks = 0; ks < 8; ++ks) {
    if (ks + 1 < 8) {
      int k1 = (ks + 1) << 5;
      stage_tile(Ab, As[cur ^ 1], lane, w, k1);
      stage_tile(Bb, Bs[cur ^ 1], lane, w, k1);
      cfence();
      asm volatile("s_waitcnt vmcnt(4)" ::: "memory");
    } else {
      cfence();
      asm volatile("s_waitcnt vmcnt(0)" ::: "memory");
    }
    spin();
    __builtin_amdgcn_s_barrier();
    spin();
    __builtin_amdgcn_s_setprio(1);
    mfma16(As[cur], Bs[cur], wi, wp, m, quad, acc);
    __builtin_amdgcn_s_setprio(0);
    spin();
    __builtin_amdgcn_s_barrier();
    spin();
    cur ^= 1;
  }
  int diag = (it0 == kt0);
  u16* dst = CBm + ((size_t)sj * CK + it0) * CK + kt0;
#pragma unroll
  for (int r = 0; r < 4; ++r)
#pragma unroll
    for (int rg = 0; rg < 4; ++rg) {
      int irow = wi + (r << 4) + (quad << 2) + rg;
#pragma unroll
      for (int c = 0; c < 4; ++c) {
        int kcol = wp + (c << 4) + m;
        float v = acc[r][c][rg];
        if (diag && kcol > irow) v = 0.f;
        dst[(size_t)irow * CK + kcol] = f2bf(v);
      }
    }
}

// ---- states: prevT[inst][p][n] = e^{cs_last} * sum_k xs[p,k]*B[n,k] ----------
// Merged ntiles; depth-2 counted-vmcnt triple-buffer pipeline + XCD swizzle.
__global__ __launch_bounds__(512) void kstates(const u16* __restrict__ xsT,
                                               const u16* __restrict__ BbfT,
                                               const float* __restrict__ cdecb,
                                               u16* __restrict__ prevT) {
  int bid = blockIdx.x;                 // 1024 = 8 XCD * 128
  int inst = ((bid & 7) << 7) + (bid >> 3);
  int h = inst & 15, sj = inst >> 4;
  __shared__ u16 As[3][128 * 32];
  __shared__ u16 Bs[3][256 * 32];
  int tid = threadIdx.x;
  int w = tid >> 6, lane = tid & 63;
  int wi = (w >> 2) << 6;               // p tile: 0,64
  int wp = (w & 3) << 6;                // n tile: 0,64,128,192
  int m = lane & 15, quad = lane >> 4;
  const u16* Ab = xsT + (size_t)inst * (128 * 256);        // rows p
  const u16* Bb = BbfT + (size_t)sj * DS * CK;             // rows n (256)
  f32x4 zini = {0.f, 0.f, 0.f, 0.f};
  f32x4 acc[4][4];
#pragma unroll
  for (int r = 0; r < 4; ++r)
#pragma unroll
    for (int c = 0; c < 4; ++c) acc[r][c] = zini;
  // prologue: prefetch steps 0 and 1 (3 loads/thread each)
  stage_half(Ab, As[0], lane, w, 0);
  stage_tile(Bb, Bs[0], lane, w, 0);
  stage_half(Ab, As[1], lane, w, 32);
  stage_tile(Bb, Bs[1], lane, w, 32);
  int cur = 0;
  for (int ks = 0; ks < 8; ++ks) {
    if (ks + 2 < 8) {
      int nb = cur + 2; if (nb >= 3) nb -= 3;
      int k2 = (ks + 2) << 5;
      stage_half(Ab, As[nb], lane, w, k2);
      stage_tile(Bb, Bs[nb], lane, w, k2);
      cfence();
      asm volatile("s_waitcnt vmcnt(6)" ::: "memory");
    } else if (ks == 6) {
      cfence();
      asm volatile("s_waitcnt vmcnt(3)" ::: "memory");
    } else {
      cfence();
      asm volatile("s_waitcnt vmcnt(0)" ::: "memory");
    }
    spin();
    __builtin_amdgcn_s_barrier();
    spin();
    __builtin_amdgcn_s_setprio(1);
    mfma16(As[cur], Bs[cur], wi, wp, m, quad, acc);
    __builtin_amdgcn_s_setprio(0);
    spin();
    __builtin_amdgcn_s_barrier();
    spin();
    cur = (cur == 2) ? 0 : cur + 1;
  }
  float scale = cdecb[sj * NH + h];
  u16* dst = prevT + (size_t)inst * (128 * 256);
#pragma unroll
  for (int r = 0; r < 4; ++r)
#pragma unroll
    for (int rg = 0; rg < 4; ++rg) {
      int prow = wi + (r << 4) + (quad << 2) + rg;
#pragma unroll
      for (int c = 0; c < 4; ++c) {
        int ncol = wp + (c << 4) + m;
        dst[(size_t)prow * 256 + ncol] = f2bf(acc[r][c][rg] * scale);
      }
    }
}

// ---- inter-chunk recurrence over prevT[s][j][h][p][n] ------------------------
__global__ __launch_bounds__(256) void kscan(u16* __restrict__ prevT,
                                             const float* __restrict__ cdecb) {
  int g = blockIdx.x * 256 + threadIdx.x;
  int n = g & 255;
  int p = (g >> 8) & 127;
  int h = (g >> 15) & 15;
  int s = g >> 19;
  size_t base = (((size_t)(s * 256 + h) * 128) + p) * 256 + n;
  const size_t stride = (size_t)NH * 128 * 256;
  float carry = 0.f;
  for (int j = 0; j < NCH; ++j) {
    size_t idx = base + (size_t)j * stride;
    float sv = bf2f(prevT[idx]);
    prevT[idx] = f2bf(carry);
    carry = carry * cdecb[(s * NCH + j) * NH + h] + sv;
  }
}

// ---- y[i,p] = e^{cs_i} * ( CBm(i,:)·xs(:,p) + C(i,:)·prev(:,p) ) -------------
// Merged itiles; depth-2 counted-vmcnt triple-buffer pipeline + XCD swizzle.
// A is always staged (uniform 3 loads/thread for exact vmcnt); the garbage
// CBm (0,1) quadrant's MFMA is skipped so it never enters acc.
__global__ __launch_bounds__(512) void ky(const u16* __restrict__ CBm,
                                          const u16* __restrict__ Cbf,
                                          const u16* __restrict__ xsT,
                                          const u16* __restrict__ prevT,
                                          const float* __restrict__ csb,
                                          u16* __restrict__ ytmpb) {
  int bid = blockIdx.x;                 // 1024 = 8 XCD * 128
  int inst = ((bid & 7) << 7) + (bid >> 3);
  int h = inst & 15, sj = inst >> 4;
  int s = sj >> 4, j = sj & 15;
  __shared__ u16 As[3][256 * 32];
  __shared__ u16 Bs[3][128 * 32];
  int tid = threadIdx.x;
  int w = tid >> 6, lane = tid & 63;
  int wi = (w >> 1) << 6;               // i tile: 0,64,128,192
  int wp = (w & 1) << 6;                // p tile: 0,64
  int m = lane & 15, quad = lane >> 4;

  const u16* Ai = CBm + (size_t)sj * CK * CK;              // rows i (256)
  const u16* Ae = Cbf + ((size_t)s * SL + j * CK) * DS;    // rows i (256)
  const u16* Bi = xsT + (size_t)inst * (128 * 256);        // rows p (128)
  const u16* Be = prevT + (size_t)inst * (128 * 256);      // rows p (128)

  f32x4 zini = {0.f, 0.f, 0.f, 0.f};
  f32x4 acc[4][4];
#pragma unroll
  for (int r = 0; r < 4; ++r)
#pragma unroll
    for (int c = 0; c < 4; ++c) acc[r][c] = zini;

  // prologue: prefetch steps 0 and 1
  stage_tile(Ai, As[0], lane, w, 0);
  stage_half(Bi, Bs[0], lane, w, 0);
  stage_tile(Ai, As[1], lane, w, 32);
  stage_half(Bi, Bs[1], lane, w, 32);
  int cur = 0;
  for (int ks = 0; ks < 16; ++ks) {
    if (ks + 2 < 16) {
      int ksn = ks + 2;
      int intran = ksn < 8;
      int k2 = (intran ? ksn : ksn - 8) << 5;
      int nb = cur + 2; if (nb >= 3) nb -= 3;
      stage_tile(intran ? Ai : Ae, As[nb], lane, w, k2);
      stage_half(intran ? Bi : Be, Bs[nb], lane, w, k2);
      cfence();
      asm volatile("s_waitcnt vmcnt(6)" ::: "memory");
    } else if (ks == 14) {
      cfence();
      asm volatile("s_waitcnt vmcnt(3)" ::: "memory");
    } else {
      cfence();
      asm volatile("s_waitcnt vmcnt(0)" ::: "memory");
    }
    spin();
    __builtin_amdgcn_s_barrier();
    spin();
    __builtin_amdgcn_s_setprio(1);
    if (ks >= 8 || ks < 4 || wi >= 128)
      mfma16(As[cur], Bs[cur], wi, wp, m, quad, acc);
    __builtin_amdgcn_s_setprio(0);
    spin();
    __builtin_amdgcn_s_barrier();
    spin();
    cur = (cur == 2) ? 0 : cur + 1;
  }
  const float* csrow = csb + ((size_t)sj * NH + h) * CK;
  u16* yb = ytmpb + ((size_t)s * SL + j * CK) * DI + h * HD;
#pragma unroll
  for (int r = 0; r < 4; ++r)
#pragma unroll
    for (int rg = 0; rg < 4; ++rg) {
      int irow = wi + (r << 4) + (quad << 2) + rg;
      float esc = expf(csrow[irow]);
#pragma unroll
      for (int c = 0; c < 4; ++c) {
        int pcol = wp + (c << 4) + m;
        yb[(size_t)irow * DI + pcol] = f2bf(acc[r][c][rg] * esc);
      }
    }
}

// ---- gate GEMV: gates[b][t][h] = x[b,t,:]·W[h,:] + D[h] ---------------------
__global__ __launch_bounds__(256) void kgate(const float* __restrict__ xg,
                                             const float* __restrict__ Wg,
                                             const float* __restrict__ Dg,
                                             float* __restrict__ gates) {
  int bid = blockIdx.x;                 // NB*SL/16 = 512 blocks
  int b = bid >> 8;
  int t0 = (bid & 255) << 4;            // 16 rows per block
  __shared__ float Wl[16 * 256];        // one 256-col slice of W, f32
  int tid = threadIdx.x;
  int w = tid >> 6, lane = tid & 63;
  int c4 = lane << 2;

  float acc[4][16];
#pragma unroll
  for (int r = 0; r < 4; ++r)
#pragma unroll
    for (int h = 0; h < 16; ++h) acc[r][h] = 0.f;

  for (int i = 0; i < 8; ++i) {
    __syncthreads();                    // protect Wl from prior-iter readers
#pragma unroll
    for (int q = 0; q < 4; ++q) {
      int idx = q * 256 + tid;          // float4 index into the [16][256] slice
      int h = idx >> 6;
      int c = (idx & 63) << 2;
      *(float4*)&Wl[h * 256 + c] = *(const float4*)&Wg[(size_t)h * DI + i * 256 + c];
    }
    __syncthreads();
    float4 Wf[16];
#pragma unroll
    for (int h = 0; h < 16; ++h) Wf[h] = *(const float4*)&Wl[h * 256 + c4];
    // wave w handles rows t0 + w*4 .. +3; W regs reused across the 4 rows
#pragma unroll
    for (int r = 0; r < 4; ++r) {
      int t = t0 + (w << 2) + r;
      float4 xv = *(const float4*)&xg[((size_t)(b * SL + t)) * DI + i * 256 + c4];
#pragma unroll
      for (int h = 0; h < 16; ++h)
        acc[r][h] += xv.x * Wf[h].x + xv.y * Wf[h].y + xv.z * Wf[h].z + xv.w * Wf[h].w;
    }
  }
  // cross-lane reduce (64 lanes each hold a disjoint 128-col partial)
#pragma unroll
  for (int r = 0; r < 4; ++r)
#pragma unroll
    for (int h = 0; h < 16; ++h) {
      float v = acc[r][h];
      v += __shfl_xor(v, 32);
      v += __shfl_xor(v, 16);
      v += __shfl_xor(v, 8);
      v += __shfl_xor(v, 4);
      v += __shfl_xor(v, 2);
      v += __shfl_xor(v, 1);
      acc[r][h] = v;
    }
  if (lane == 0) {
#pragma unroll
    for (int r = 0; r < 4; ++r) {
      int t = t0 + (w << 2) + r;
      float* gdst = gates + ((size_t)(b * SL + t)) * NH;
#pragma unroll
      for (int h = 0; h < 16; ++h) gdst[h] = acc[r][h] + Dg[h];
    }
  }
}

// ---- final stream: out = roll(y_fw) + flip(roll(y_bw)) + x * gate ------------
__device__ __forceinline__ void unpk8(uint4 u, float* o) {
  o[0] = __uint_as_float(u.x << 16); o[1] = __uint_as_float(u.x & 0xffff0000u);
  o[2] = __uint_as_float(u.y << 16); o[3] = __uint_as_float(u.y & 0xffff0000u);
  o[4] = __uint_as_float(u.z << 16); o[5] = __uint_as_float(u.z & 0xffff0000u);
  o[6] = __uint_as_float(u.w << 16); o[7] = __uint_as_float(u.w & 0xffff0000u);
}

// 2048 blocks x 4 rows: no LDS, no barriers, pure coalesced streaming.
__global__ __launch_bounds__(256) void kstream(const float* __restrict__ xg,
                                               const float* __restrict__ gates,
                                               const u16* __restrict__ ytmpb,
                                               float* __restrict__ out) {
  int bid = blockIdx.x;                 // NB*SL/4 = 2048 blocks
  int b = bid >> 10;
  int t0 = (bid & 1023) << 2;           // 4 rows per block
  int tid = threadIdx.x;
  int d0 = tid << 3;
  int h8 = tid >> 4;                    // = d0 >> 7
  const u16* fwbase = ytmpb + (size_t)b * SL * DI + d0;
  const u16* bwbase = ytmpb + (size_t)(2 + b) * SL * DI + d0;
#pragma unroll
  for (int r = 0; r < 4; ++r) {
    int t = t0 + r;
    size_t rowb = ((size_t)(b * SL + t)) * DI + d0;
    float4 x0 = *(const float4*)&xg[rowb];
    float4 x1 = *(const float4*)&xg[rowb + 4];
    float fy[8] = {0.f, 0.f, 0.f, 0.f, 0.f, 0.f, 0.f, 0.f};
    float by[8] = {0.f, 0.f, 0.f, 0.f, 0.f, 0.f, 0.f, 0.f};
    if (t > 0) unpk8(*(const uint4*)(fwbase + (size_t)(t - 1) * DI), fy);
    if (t < SL - 1) unpk8(*(const uint4*)(bwbase + (size_t)(SL - 2 - t) * DI), by);
    float g = gates[((size_t)(b * SL + t)) * NH + h8];
    float4 o0, o1;
    o0.x = fy[0] + by[0] + x0.x * g;
    o0.y = fy[1] + by[1] + x0.y * g;
    o0.z = fy[2] + by[2] + x0.z * g;
    o0.w = fy[3] + by[3] + x0.w * g;
    o1.x = fy[4] + by[4] + x1.x * g;
    o1.y = fy[5] + by[5] + x1.y * g;
    o1.z = fy[6] + by[6] + x1.z * g;
    o1.w = fy[7] + by[7] + x1.w * g;
    *(float4*)&out[rowb] = o0;
    *(float4*)&out[rowb + 4] = o1;
  }
}

extern "C" void kernel_launch(void* const* d_in, const int* in_sizes, int n_in,
                              void* d_out, int out_size, void* d_ws, size_t ws_size,
                              hipStream_t stream) {
  (void)in_sizes; (void)n_in; (void)out_size; (void)ws_size;
  const float* x     = (const float*)d_in[0];
  const float* BC    = (const float*)d_in[1];
  const float* dt    = (const float*)d_in[2];
  const float* A_log = (const float*)d_in[3];
  const float* Dg    = (const float*)d_in[4];
  const float* W     = (const float*)d_in[5];
  float* out = (float*)d_out;

  char* p = (char*)d_ws;
  float* cs    = (float*)p; p += (size_t)NSQ * NCH * NH * CK * 4;        // 1 MB
  float* dtv   = (float*)p; p += (size_t)NSQ * NCH * NH * CK * 4;        // 1 MB
  float* cdec  = (float*)p; p += (size_t)NSQ * NCH * NH * 4;             // 4 KB
  float* gates = (float*)p; p += (size_t)NB * SL * NH * 4;               // 512 KB
  u16* Bbf    = (u16*)p;    p += (size_t)NSQ * SL * DS * 2;              // 8.4 MB
  u16* Cbf    = (u16*)p;    p += (size_t)NSQ * SL * DS * 2;              // 8.4 MB
  u16* BbfT   = (u16*)p;    p += (size_t)NSQ * NCH * DS * CK * 2;        // 8.4 MB
  u16* CBm    = (u16*)p;    p += (size_t)NSQ * NCH * CK * CK * 2;        // 8.4 MB
  u16* xsT    = (u16*)p;    p += (size_t)NSQ * NCH * NH * HD * CK * 2;   // 67 MB
  u16* prevT  = (u16*)p;    p += (size_t)NSQ * NCH * NH * HD * DS * 2;   // 67 MB
  u16* ytmpb  = (u16*)p;    p += (size_t)NSQ * SL * DI * 2;              // 67 MB

  hipLaunchKernelGGL(kgate,   dim3(NB * SL / 16),        dim3(256), 0, stream, x, W, Dg, gates);
  hipLaunchKernelGGL(kprep,   dim3(NSQ * NCH * NH),      dim3(CK),  0, stream, dt, A_log, cs, dtv, cdec);
  hipLaunchKernelGGL(kcast,   dim3(NSQ * SL / 8),        dim3(256), 0, stream, BC, Bbf, Cbf);
  hipLaunchKernelGGL(ktransB, dim3(NSQ * NCH * 4),       dim3(256), 0, stream, Bbf, BbfT);
  hipLaunchKernelGGL(kxsT,    dim3(NSQ * NCH * NH),      dim3(256), 0, stream, x, cs, dtv, xsT);
  hipLaunchKernelGGL(kcb,     dim3(NSQ * NCH * 3),       dim3(256), 0, stream, Cbf, Bbf, CBm);
  hipLaunchKernelGGL(kstates, dim3(NSQ * NCH * NH),      dim3(512), 0, stream, xsT, BbfT, cdec, prevT);
  hipLaunchKernelGGL(kscan,   dim3(NSQ * NH * HD * DS / 256), dim3(256), 0, stream, prevT, cdec);
  hipLaunchKernelGGL(ky,      dim3(NSQ * NCH * NH),      dim3(512), 0, stream, CBm, Cbf, xsT, prevT, cs, ytmpb);
  hipLaunchKernelGGL(kstream, dim3(NB * SL / 4),         dim3(256), 0, stream, x, gates, ytmpb, out);
}

// Round 10
// 355.772 us; speedup vs baseline: 1.0471x; 1.0471x over previous
//
#include <hip/hip_runtime.h>
#include <stdint.h>

#define NB 2
#define SL 4096
#define NH 16
#define HD 128
#define DS 256
#define CK 256
#define NCH 16
#define NSQ 4
#define DI 2048

typedef unsigned short u16;
typedef unsigned int u32;
typedef __attribute__((ext_vector_type(8))) __bf16 bf16x8;
typedef __attribute__((ext_vector_type(4))) float f32x4;

__device__ __forceinline__ int tor(int dir, int t) { return dir ? (SL - 1 - t) : t; }

__device__ __forceinline__ u16 f2bf(float f) {
  u32 u = __float_as_uint(f);
  u = u + 0x7fffu + ((u >> 16) & 1u);   // RNE
  return (u16)(u >> 16);
}
__device__ __forceinline__ float bf2f(u16 s) {
  return __uint_as_float(((u32)s) << 16);
}

__device__ __forceinline__ void gl_lds16(const u16* g, u16* l) {
  __builtin_amdgcn_global_load_lds((const __attribute__((address_space(1))) u32*)g,
                                   (__attribute__((address_space(3))) u32*)l, 16, 0, 0);
}

__device__ __forceinline__ void cfence() { asm volatile("" ::: "memory"); }
__device__ __forceinline__ void spin() { __builtin_amdgcn_sched_barrier(0); }

// Stage a 32-row slice of a tile (row stride 256 elems in global) into LDS rows
// [w*32, w*32+32) of a [*][32] buffer, 16B chunks XOR-swizzled by ((row>>1)&3).
// 2 gl_lds per thread.
__device__ __forceinline__ void stage_tile(const u16* __restrict__ src, u16* lds,
                                           int lane, int w, int k0) {
  int sgrow = lane >> 2, sc = lane & 3;
  int r0 = w << 5;
  int ra = r0 + sgrow, rb = ra + 16;
  int kqa = (sc ^ ((ra >> 1) & 3)) << 3;
  int kqb = (sc ^ ((rb >> 1) & 3)) << 3;
  gl_lds16(src + (size_t)ra * 256 + k0 + kqa, lds + r0 * 32);
  gl_lds16(src + (size_t)rb * 256 + k0 + kqb, lds + (r0 + 16) * 32);
}

// 8 waves (512 threads) stage a 128x32 tile: wave w stages rows [w*16, w*16+16),
// 1 gl_lds per thread. Same swizzle as stage_tile.
__device__ __forceinline__ void stage_half(const u16* __restrict__ src, u16* lds,
                                           int lane, int w, int k0) {
  int row = (w << 4) + (lane >> 2);
  int sc = lane & 3;
  int kq = (sc ^ ((row >> 1) & 3)) << 3;
  gl_lds16(src + (size_t)row * 256 + k0 + kq, lds + (w << 4) * 32);
}

__device__ __forceinline__ bf16x8 frag(const u16* lds, int base_row, int m, int quad) {
  int row = base_row + m;
  return *(const bf16x8*)&lds[row * 32 + ((quad ^ ((row >> 1) & 3)) << 3)];
}

__device__ __forceinline__ void mfma16(const u16* As, const u16* Bs, int wi, int wp,
                                       int m, int quad, f32x4 acc[4][4]) {
  bf16x8 af[4], bv[4];
#pragma unroll
  for (int r = 0; r < 4; ++r) af[r] = frag(As, wi + (r << 4), m, quad);
#pragma unroll
  for (int c = 0; c < 4; ++c) bv[c] = frag(Bs, wp + (c << 4), m, quad);
#pragma unroll
  for (int r = 0; r < 4; ++r)
#pragma unroll
    for (int c = 0; c < 4; ++c)
      acc[r][c] = __builtin_amdgcn_mfma_f32_16x16x32_bf16(af[r], bv[c], acc[r][c], 0, 0, 0);
}

// ---- prep: softplus(dt), per-chunk cumsum of dA -----------------------------
__global__ __launch_bounds__(256) void kprep(const float* __restrict__ dt,
                                             const float* __restrict__ A_log,
                                             float* __restrict__ csb,
                                             float* __restrict__ dtvb,
                                             float* __restrict__ cdecb) {
  int blk = blockIdx.x;                 // sj*16 + h
  int h = blk & 15, sj = blk >> 4;
  int s = sj >> 4, j = sj & 15;
  int b = s & 1, dir = s >> 1;
  int i = threadIdx.x;
  int to = tor(dir, j * CK + i);
  __shared__ float sbuf[CK];
  float a = -expf(A_log[h]);
  float raw = dt[((size_t)(b * SL + to)) * (2 * NH) + dir * NH + h];
  float sp = (raw > 20.f) ? raw : log1pf(expf(raw));
  sbuf[i] = sp * a;
  __syncthreads();
  for (int off = 1; off < CK; off <<= 1) {
    float v = (i >= off) ? sbuf[i - off] : 0.f;
    __syncthreads();
    sbuf[i] += v;
    __syncthreads();
  }
  float csv = sbuf[i];
  size_t base = ((size_t)sj * NH + h) * CK;
  csb[base + i] = csv;
  dtvb[base + i] = sp;
  if (i == CK - 1) cdecb[sj * NH + h] = expf(csv);
}

// ---- cast BC -> bf16 B/C with flip applied: [s][t][n], vectorized ------------
__global__ __launch_bounds__(256) void kcast(const float* __restrict__ BC,
                                             u16* __restrict__ Bbf,
                                             u16* __restrict__ Cbf) {
  int blk = blockIdx.x;                 // s*(SL/8) + tg
  int s = blk >> 9, tg = blk & 511;
  int b = s & 1, dir = s >> 1;
  int tid = threadIdx.x;
  int rr = tid >> 6, q = tid & 63;      // 4 rows per iter, 64 threads per row
  int isC = q >> 5, qq = q & 31;
#pragma unroll
  for (int it = 0; it < 2; ++it) {
    int t = tg * 8 + it * 4 + rr;
    int tsrc = tor(dir, t);
    const float* src = BC + ((size_t)(b * SL + tsrc)) * (2 * DS) + q * 8;
    float4 v0 = ((const float4*)src)[0];
    float4 v1 = ((const float4*)src)[1];
    uint4 wv;
    wv.x = (u32)f2bf(v0.x) | ((u32)f2bf(v0.y) << 16);
    wv.y = (u32)f2bf(v0.z) | ((u32)f2bf(v0.w) << 16);
    wv.z = (u32)f2bf(v1.x) | ((u32)f2bf(v1.y) << 16);
    wv.w = (u32)f2bf(v1.z) | ((u32)f2bf(v1.w) << 16);
    u16* dstb = (isC ? Cbf : Bbf) + ((size_t)s * SL + t) * DS + qq * 8;
    *(uint4*)dstb = wv;
  }
}

// ---- transpose B within chunk: BbfT[sj][n][k], one k-slice per block ---------
__global__ __launch_bounds__(256) void ktransB(const u16* __restrict__ Bbf,
                                               u16* __restrict__ BbfT) {
  int blk = blockIdx.x;                 // sj*4 + kslice
  int kslice = blk & 3, sj = blk >> 2;
  int k0 = kslice << 6;
  int s = sj >> 4, j = sj & 15;
  __shared__ u16 T[64 * 264];
  int tid = threadIdx.x;
  const u16* src = Bbf + ((size_t)s * SL + j * CK) * DS;
  u16* dst = BbfT + (size_t)sj * DS * CK;
  int kr = tid >> 2, part = (tid & 3) * 64;
  {
    const uint4* gs = (const uint4*)(src + (size_t)(k0 + kr) * DS + part);
    uint4* tb = (uint4*)&T[kr * 264 + part];
#pragma unroll
    for (int q = 0; q < 8; ++q) tb[q] = gs[q];
  }
  __syncthreads();
  int n = tid;
  u16 col[64];
#pragma unroll
  for (int kq = 0; kq < 64; ++kq) col[kq] = T[kq * 264 + n];
  uint4* ds_ = (uint4*)(dst + (size_t)n * CK + k0);
#pragma unroll
  for (int q = 0; q < 8; ++q) {
    uint4 wv;
    wv.x = (u32)col[q * 8 + 0] | ((u32)col[q * 8 + 1] << 16);
    wv.y = (u32)col[q * 8 + 2] | ((u32)col[q * 8 + 3] << 16);
    wv.z = (u32)col[q * 8 + 4] | ((u32)col[q * 8 + 5] << 16);
    wv.w = (u32)col[q * 8 + 6] | ((u32)col[q * 8 + 7] << 16);
    ds_[q] = wv;
  }
}

// ---- xsT[inst][p][k] = bf16( x[t(k)][h*128+p] * e^{-cs_k} * dt_k ) ----------
__global__ __launch_bounds__(256) void kxsT(const float* __restrict__ xg,
                                            const float* __restrict__ csb,
                                            const float* __restrict__ dtvb,
                                            u16* __restrict__ xsT) {
  int inst = blockIdx.x;                // ((s*16+j)*16+h)
  int h = inst & 15, sj = inst >> 4;
  int s = sj >> 4, j = sj & 15;
  int b = s & 1, dir = s >> 1;
  int tid = threadIdx.x;
  __shared__ u16 Ls[128 * 40];          // [p][kk], stride 40
  size_t cbase = ((size_t)sj * NH + h) * CK;
  u16* dst = xsT + (size_t)inst * (128 * 256);
  int kk = tid >> 3;
  int pg = (tid & 7) * 16;
  int p2 = tid >> 1, half = tid & 1;
  for (int k0 = 0; k0 < CK; k0 += 32) {
    int kglob = k0 + kk;
    float sc_ = expf(-csb[cbase + kglob]) * dtvb[cbase + kglob];
    int t = tor(dir, j * CK + kglob);
    const float* src = xg + ((size_t)(b * SL + t)) * DI + h * HD + pg;
    float4 v0 = ((const float4*)src)[0];
    float4 v1 = ((const float4*)src)[1];
    float4 v2 = ((const float4*)src)[2];
    float4 v3 = ((const float4*)src)[3];
    float vv[16] = {v0.x, v0.y, v0.z, v0.w, v1.x, v1.y, v1.z, v1.w,
                    v2.x, v2.y, v2.z, v2.w, v3.x, v3.y, v3.z, v3.w};
    __syncthreads();
#pragma unroll
    for (int q = 0; q < 16; ++q) Ls[(pg + q) * 40 + kk] = f2bf(vv[q] * sc_);
    __syncthreads();
    uint4 w0 = *(const uint4*)&Ls[p2 * 40 + half * 16];
    uint4 w1 = *(const uint4*)&Ls[p2 * 40 + half * 16 + 8];
    *(uint4*)&dst[(size_t)p2 * 256 + k0 + half * 16] = w0;
    *(uint4*)&dst[(size_t)p2 * 256 + k0 + half * 16 + 8] = w1;
  }
}

// ---- CBm[sj][i][k] = bf16( sum_n C[i,n]*B[k,n] ), masked k<=i ---------------
// Counted-vmcnt double-buffered pipeline + XCD-bijective block swizzle.
__global__ __launch_bounds__(256) void kcb(const u16* __restrict__ Cbf,
                                           const u16* __restrict__ Bbf,
                                           u16* __restrict__ CBm) {
  int bid = blockIdx.x;                 // 192 = 8 XCD * 24
  int g = ((bid & 7) * 24) + (bid >> 3);
  int tri = g % 3;                      // 0:(0,0) 1:(1,0) 2:(1,1)
  int sj = g / 3;
  int it0 = tri ? 128 : 0;
  int kt0 = (tri == 2) ? 128 : 0;
  int s = sj >> 4, j = sj & 15;
  __shared__ u16 As[2][128 * 32];
  __shared__ u16 Bs[2][128 * 32];
  int tid = threadIdx.x;
  int w = tid >> 6, lane = tid & 63;
  int wi = (w >> 1) << 6, wp = (w & 1) << 6;
  int m = lane & 15, quad = lane >> 4;
  const u16* Ab = Cbf + ((size_t)s * SL + j * CK + it0) * DS;
  const u16* Bb = Bbf + ((size_t)s * SL + j * CK + kt0) * DS;
  f32x4 zini = {0.f, 0.f, 0.f, 0.f};
  f32x4 acc[4][4];
#pragma unroll
  for (int r = 0; r < 4; ++r)
#pragma unroll
    for (int c = 0; c < 4; ++c) acc[r][c] = zini;
  stage_tile(Ab, As[0], lane, w, 0);
  stage_tile(Bb, Bs[0], lane, w, 0);
  int cur = 0;
  for (int ks = 0; ks < 8; ++ks) {
    if (ks + 1 < 8) {
      int k1 = (ks + 1) << 5;
      stage_tile(Ab, As[cur ^ 1], lane, w, k1);
      stage_tile(Bb, Bs[cur ^ 1], lane, w, k1);
      cfence();
      asm volatile("s_waitcnt vmcnt(4)" ::: "memory");
    } else {
      cfence();
      asm volatile("s_waitcnt vmcnt(0)" ::: "memory");
    }
    spin();
    __builtin_amdgcn_s_barrier();
    spin();
    mfma16(As[cur], Bs[cur], wi, wp, m, quad, acc);
    spin();
    __builtin_amdgcn_s_barrier();
    spin();
    cur ^= 1;
  }
  int diag = (it0 == kt0);
  u16* dst = CBm + ((size_t)sj * CK + it0) * CK + kt0;
#pragma unroll
  for (int r = 0; r < 4; ++r)
#pragma unroll
    for (int rg = 0; rg < 4; ++rg) {
      int irow = wi + (r << 4) + (quad << 2) + rg;
#pragma unroll
      for (int c = 0; c < 4; ++c) {
        int kcol = wp + (c << 4) + m;
        float v = acc[r][c][rg];
        if (diag && kcol > irow) v = 0.f;
        dst[(size_t)irow * CK + kcol] = f2bf(v);
      }
    }
}

// ---- states: prevT[inst][p][n] = e^{cs_last} * sum_k xs[p,k]*B[n,k] ----------
// Merged ntiles + counted-vmcnt double-buffer + XCD-bijective block swizzle.
__global__ __launch_bounds__(512) void kstates(const u16* __restrict__ xsT,
                                               const u16* __restrict__ BbfT,
                                               const float* __restrict__ cdecb,
                                               u16* __restrict__ prevT) {
  int bid = blockIdx.x;                 // 1024 = 8 XCD * 128
  int inst = ((bid & 7) << 7) + (bid >> 3);
  int h = inst & 15, sj = inst >> 4;
  __shared__ u16 As[2][128 * 32];
  __shared__ u16 Bs[2][256 * 32];
  int tid = threadIdx.x;
  int w = tid >> 6, lane = tid & 63;
  int wi = (w >> 2) << 6;               // p tile: 0,64
  int wp = (w & 3) << 6;                // n tile: 0,64,128,192
  int m = lane & 15, quad = lane >> 4;
  const u16* Ab = xsT + (size_t)inst * (128 * 256);        // rows p
  const u16* Bb = BbfT + (size_t)sj * DS * CK;             // rows n (256)
  f32x4 zini = {0.f, 0.f, 0.f, 0.f};
  f32x4 acc[4][4];
#pragma unroll
  for (int r = 0; r < 4; ++r)
#pragma unroll
    for (int c = 0; c < 4; ++c) acc[r][c] = zini;
  stage_half(Ab, As[0], lane, w, 0);
  stage_tile(Bb, Bs[0], lane, w, 0);
  int cur = 0;
  for (int ks = 0; ks < 8; ++ks) {
    if (ks + 1 < 8) {
      int k1 = (ks + 1) << 5;
      stage_half(Ab, As[cur ^ 1], lane, w, k1);
      stage_tile(Bb, Bs[cur ^ 1], lane, w, k1);
      cfence();
      asm volatile("s_waitcnt vmcnt(3)" ::: "memory");
    } else {
      cfence();
      asm volatile("s_waitcnt vmcnt(0)" ::: "memory");
    }
    spin();
    __builtin_amdgcn_s_barrier();
    spin();
    mfma16(As[cur], Bs[cur], wi, wp, m, quad, acc);
    spin();
    __builtin_amdgcn_s_barrier();
    spin();
    cur ^= 1;
  }
  float scale = cdecb[sj * NH + h];
  u16* dst = prevT + (size_t)inst * (128 * 256);
#pragma unroll
  for (int r = 0; r < 4; ++r)
#pragma unroll
    for (int rg = 0; rg < 4; ++rg) {
      int prow = wi + (r << 4) + (quad << 2) + rg;
#pragma unroll
      for (int c = 0; c < 4; ++c) {
        int ncol = wp + (c << 4) + m;
        dst[(size_t)prow * 256 + ncol] = f2bf(acc[r][c][rg] * scale);
      }
    }
}

// ---- inter-chunk recurrence over prevT[s][j][h][p][n] ------------------------
__global__ __launch_bounds__(256) void kscan(u16* __restrict__ prevT,
                                             const float* __restrict__ cdecb) {
  int g = blockIdx.x * 256 + threadIdx.x;
  int n = g & 255;
  int p = (g >> 8) & 127;
  int h = (g >> 15) & 15;
  int s = g >> 19;
  size_t base = (((size_t)(s * 256 + h) * 128) + p) * 256 + n;
  const size_t stride = (size_t)NH * 128 * 256;
  float carry = 0.f;
  for (int j = 0; j < NCH; ++j) {
    size_t idx = base + (size_t)j * stride;
    float sv = bf2f(prevT[idx]);
    prevT[idx] = f2bf(carry);
    carry = carry * cdecb[(s * NCH + j) * NH + h] + sv;
  }
}

// ---- y[i,p] = e^{cs_i} * ( CBm(i,:)·xs(:,p) + C(i,:)·prev(:,p) ) -------------
// Merged itiles + counted-vmcnt double-buffer + XCD-bijective block swizzle.
// A is always staged (uniform 3 loads/thread for exact vmcnt); the garbage
// CBm (0,1) quadrant's MFMA is skipped so it never enters acc.
__global__ __launch_bounds__(512) void ky(const u16* __restrict__ CBm,
                                          const u16* __restrict__ Cbf,
                                          const u16* __restrict__ xsT,
                                          const u16* __restrict__ prevT,
                                          const float* __restrict__ csb,
                                          u16* __restrict__ ytmpb) {
  int bid = blockIdx.x;                 // 1024 = 8 XCD * 128
  int inst = ((bid & 7) << 7) + (bid >> 3);
  int h = inst & 15, sj = inst >> 4;
  int s = sj >> 4, j = sj & 15;
  __shared__ u16 As[2][256 * 32];
  __shared__ u16 Bs[2][128 * 32];
  int tid = threadIdx.x;
  int w = tid >> 6, lane = tid & 63;
  int wi = (w >> 1) << 6;               // i tile: 0,64,128,192
  int wp = (w & 1) << 6;                // p tile: 0,64
  int m = lane & 15, quad = lane >> 4;

  const u16* Ai = CBm + (size_t)sj * CK * CK;              // rows i (256)
  const u16* Ae = Cbf + ((size_t)s * SL + j * CK) * DS;    // rows i (256)
  const u16* Bi = xsT + (size_t)inst * (128 * 256);        // rows p (128)
  const u16* Be = prevT + (size_t)inst * (128 * 256);      // rows p (128)

  f32x4 zini = {0.f, 0.f, 0.f, 0.f};
  f32x4 acc[4][4];
#pragma unroll
  for (int r = 0; r < 4; ++r)
#pragma unroll
    for (int c = 0; c < 4; ++c) acc[r][c] = zini;

  stage_tile(Ai, As[0], lane, w, 0);
  stage_half(Bi, Bs[0], lane, w, 0);
  int cur = 0;
  for (int ks = 0; ks < 16; ++ks) {
    if (ks + 1 < 16) {
      int ksn = ks + 1;
      int intran = ksn < 8;
      int k1 = (intran ? ksn : ksn - 8) << 5;
      stage_tile(intran ? Ai : Ae, As[cur ^ 1], lane, w, k1);
      stage_half(intran ? Bi : Be, Bs[cur ^ 1], lane, w, k1);
      cfence();
      asm volatile("s_waitcnt vmcnt(3)" ::: "memory");
    } else {
      cfence();
      asm volatile("s_waitcnt vmcnt(0)" ::: "memory");
    }
    spin();
    __builtin_amdgcn_s_barrier();
    spin();
    if (ks >= 8 || ks < 4 || wi >= 128)
      mfma16(As[cur], Bs[cur], wi, wp, m, quad, acc);
    spin();
    __builtin_amdgcn_s_barrier();
    spin();
    cur ^= 1;
  }
  const float* csrow = csb + ((size_t)sj * NH + h) * CK;
  u16* yb = ytmpb + ((size_t)s * SL + j * CK) * DI + h * HD;
#pragma unroll
  for (int r = 0; r < 4; ++r)
#pragma unroll
    for (int rg = 0; rg < 4; ++rg) {
      int irow = wi + (r << 4) + (quad << 2) + rg;
      float esc = expf(csrow[irow]);
#pragma unroll
      for (int c = 0; c < 4; ++c) {
        int pcol = wp + (c << 4) + m;
        yb[(size_t)irow * DI + pcol] = f2bf(acc[r][c][rg] * esc);
      }
    }
}

// ---- gate GEMV: gates[b][t][h] = x[b,t,:]·W[h,:] + D[h] ---------------------
__global__ __launch_bounds__(256) void kgate(const float* __restrict__ xg,
                                             const float* __restrict__ Wg,
                                             const float* __restrict__ Dg,
                                             float* __restrict__ gates) {
  int bid = blockIdx.x;                 // NB*SL/16 = 512 blocks
  int b = bid >> 8;
  int t0 = (bid & 255) << 4;            // 16 rows per block
  __shared__ float Wl[16 * 256];        // one 256-col slice of W, f32
  int tid = threadIdx.x;
  int w = tid >> 6, lane = tid & 63;
  int c4 = lane << 2;

  float acc[4][16];
#pragma unroll
  for (int r = 0; r < 4; ++r)
#pragma unroll
    for (int h = 0; h < 16; ++h) acc[r][h] = 0.f;

  for (int i = 0; i < 8; ++i) {
    __syncthreads();                    // protect Wl from prior-iter readers
#pragma unroll
    for (int q = 0; q < 4; ++q) {
      int idx = q * 256 + tid;          // float4 index into the [16][256] slice
      int h = idx >> 6;
      int c = (idx & 63) << 2;
      *(float4*)&Wl[h * 256 + c] = *(const float4*)&Wg[(size_t)h * DI + i * 256 + c];
    }
    __syncthreads();
    float4 Wf[16];
#pragma unroll
    for (int h = 0; h < 16; ++h) Wf[h] = *(const float4*)&Wl[h * 256 + c4];
    // wave w handles rows t0 + w*4 .. +3; W regs reused across the 4 rows
#pragma unroll
    for (int r = 0; r < 4; ++r) {
      int t = t0 + (w << 2) + r;
      float4 xv = *(const float4*)&xg[((size_t)(b * SL + t)) * DI + i * 256 + c4];
#pragma unroll
      for (int h = 0; h < 16; ++h)
        acc[r][h] += xv.x * Wf[h].x + xv.y * Wf[h].y + xv.z * Wf[h].z + xv.w * Wf[h].w;
    }
  }
  // cross-lane reduce (64 lanes each hold a disjoint 128-col partial)
#pragma unroll
  for (int r = 0; r < 4; ++r)
#pragma unroll
    for (int h = 0; h < 16; ++h) {
      float v = acc[r][h];
      v += __shfl_xor(v, 32);
      v += __shfl_xor(v, 16);
      v += __shfl_xor(v, 8);
      v += __shfl_xor(v, 4);
      v += __shfl_xor(v, 2);
      v += __shfl_xor(v, 1);
      acc[r][h] = v;
    }
  if (lane == 0) {
#pragma unroll
    for (int r = 0; r < 4; ++r) {
      int t = t0 + (w << 2) + r;
      float* gdst = gates + ((size_t)(b * SL + t)) * NH;
#pragma unroll
      for (int h = 0; h < 16; ++h) gdst[h] = acc[r][h] + Dg[h];
    }
  }
}

// ---- final stream: out = roll(y_fw) + flip(roll(y_bw)) + x * gate ------------
__device__ __forceinline__ void unpk8(uint4 u, float* o) {
  o[0] = __uint_as_float(u.x << 16); o[1] = __uint_as_float(u.x & 0xffff0000u);
  o[2] = __uint_as_float(u.y << 16); o[3] = __uint_as_float(u.y & 0xffff0000u);
  o[4] = __uint_as_float(u.z << 16); o[5] = __uint_as_float(u.z & 0xffff0000u);
  o[6] = __uint_as_float(u.w << 16); o[7] = __uint_as_float(u.w & 0xffff0000u);
}

// 2048 blocks x 4 rows: no LDS, no barriers, pure coalesced streaming.
__global__ __launch_bounds__(256) void kstream(const float* __restrict__ xg,
                                               const float* __restrict__ gates,
                                               const u16* __restrict__ ytmpb,
                                               float* __restrict__ out) {
  int bid = blockIdx.x;                 // NB*SL/4 = 2048 blocks
  int b = bid >> 10;
  int t0 = (bid & 1023) << 2;           // 4 rows per block
  int tid = threadIdx.x;
  int d0 = tid << 3;
  int h8 = tid >> 4;                    // = d0 >> 7
  const u16* fwbase = ytmpb + (size_t)b * SL * DI + d0;
  const u16* bwbase = ytmpb + (size_t)(2 + b) * SL * DI + d0;
#pragma unroll
  for (int r = 0; r < 4; ++r) {
    int t = t0 + r;
    size_t rowb = ((size_t)(b * SL + t)) * DI + d0;
    float4 x0 = *(const float4*)&xg[rowb];
    float4 x1 = *(const float4*)&xg[rowb + 4];
    float fy[8] = {0.f, 0.f, 0.f, 0.f, 0.f, 0.f, 0.f, 0.f};
    float by[8] = {0.f, 0.f, 0.f, 0.f, 0.f, 0.f, 0.f, 0.f};
    if (t > 0) unpk8(*(const uint4*)(fwbase + (size_t)(t - 1) * DI), fy);
    if (t < SL - 1) unpk8(*(const uint4*)(bwbase + (size_t)(SL - 2 - t) * DI), by);
    float g = gates[((size_t)(b * SL + t)) * NH + h8];
    float4 o0, o1;
    o0.x = fy[0] + by[0] + x0.x * g;
    o0.y = fy[1] + by[1] + x0.y * g;
    o0.z = fy[2] + by[2] + x0.z * g;
    o0.w = fy[3] + by[3] + x0.w * g;
    o1.x = fy[4] + by[4] + x1.x * g;
    o1.y = fy[5] + by[5] + x1.y * g;
    o1.z = fy[6] + by[6] + x1.z * g;
    o1.w = fy[7] + by[7] + x1.w * g;
    *(float4*)&out[rowb] = o0;
    *(float4*)&out[rowb + 4] = o1;
  }
}

extern "C" void kernel_launch(void* const* d_in, const int* in_sizes, int n_in,
                              void* d_out, int out_size, void* d_ws, size_t ws_size,
                              hipStream_t stream) {
  (void)in_sizes; (void)n_in; (void)out_size; (void)ws_size;
  const float* x     = (const float*)d_in[0];
  const float* BC    = (const float*)d_in[1];
  const float* dt    = (const float*)d_in[2];
  const float* A_log = (const float*)d_in[3];
  const float* Dg    = (const float*)d_in[4];
  const float* W     = (const float*)d_in[5];
  float* out = (float*)d_out;

  char* p = (char*)d_ws;
  float* cs    = (float*)p; p += (size_t)NSQ * NCH * NH * CK * 4;        // 1 MB
  float* dtv   = (float*)p; p += (size_t)NSQ * NCH * NH * CK * 4;        // 1 MB
  float* cdec  = (float*)p; p += (size_t)NSQ * NCH * NH * 4;             // 4 KB
  float* gates = (float*)p; p += (size_t)NB * SL * NH * 4;               // 512 KB
  u16* Bbf    = (u16*)p;    p += (size_t)NSQ * SL * DS * 2;              // 8.4 MB
  u16* Cbf    = (u16*)p;    p += (size_t)NSQ * SL * DS * 2;              // 8.4 MB
  u16* BbfT   = (u16*)p;    p += (size_t)NSQ * NCH * DS * CK * 2;        // 8.4 MB
  u16* CBm    = (u16*)p;    p += (size_t)NSQ * NCH * CK * CK * 2;        // 8.4 MB
  u16* xsT    = (u16*)p;    p += (size_t)NSQ * NCH * NH * HD * CK * 2;   // 67 MB
  u16* prevT  = (u16*)p;    p += (size_t)NSQ * NCH * NH * HD * DS * 2;   // 67 MB
  u16* ytmpb  = (u16*)p;    p += (size_t)NSQ * SL * DI * 2;              // 67 MB

  hipLaunchKernelGGL(kgate,   dim3(NB * SL / 16),        dim3(256), 0, stream, x, W, Dg, gates);
  hipLaunchKernelGGL(kprep,   dim3(NSQ * NCH * NH),      dim3(CK),  0, stream, dt, A_log, cs, dtv, cdec);
  hipLaunchKernelGGL(kcast,   dim3(NSQ * SL / 8),        dim3(256), 0, stream, BC, Bbf, Cbf);
  hipLaunchKernelGGL(ktransB, dim3(NSQ * NCH * 4),       dim3(256), 0, stream, Bbf, BbfT);
  hipLaunchKernelGGL(kxsT,    dim3(NSQ * NCH * NH),      dim3(256), 0, stream, x, cs, dtv, xsT);
  hipLaunchKernelGGL(kcb,     dim3(NSQ * NCH * 3),       dim3(256), 0, stream, Cbf, Bbf, CBm);
  hipLaunchKernelGGL(kstates, dim3(NSQ * NCH * NH),      dim3(512), 0, stream, xsT, BbfT, cdec, prevT);
  hipLaunchKernelGGL(kscan,   dim3(NSQ * NH * HD * DS / 256), dim3(256), 0, stream, prevT, cdec);
  hipLaunchKernelGGL(ky,      dim3(NSQ * NCH * NH),      dim3(512), 0, stream, CBm, Cbf, xsT, prevT, cs, ytmpb);
  hipLaunchKernelGGL(kstream, dim3(NB * SL / 4),         dim3(256), 0, stream, x, gates, ytmpb, out);
}

// Round 11
// 350.038 us; speedup vs baseline: 1.0642x; 1.0164x over previous
//
#include <hip/hip_runtime.h>
#include <stdint.h>

#define NB 2
#define SL 4096
#define NH 16
#define HD 128
#define DS 256
#define CK 256
#define NCH 16
#define NSQ 4
#define DI 2048

typedef unsigned short u16;
typedef unsigned int u32;
typedef __attribute__((ext_vector_type(8))) __bf16 bf16x8;
typedef __attribute__((ext_vector_type(4))) float f32x4;

__device__ __forceinline__ int tor(int dir, int t) { return dir ? (SL - 1 - t) : t; }

__device__ __forceinline__ u16 f2bf(float f) {
  u32 u = __float_as_uint(f);
  u = u + 0x7fffu + ((u >> 16) & 1u);   // RNE
  return (u16)(u >> 16);
}
__device__ __forceinline__ float bf2f(u16 s) {
  return __uint_as_float(((u32)s) << 16);
}

__device__ __forceinline__ void gl_lds16(const u16* g, u16* l) {
  __builtin_amdgcn_global_load_lds((const __attribute__((address_space(1))) u32*)g,
                                   (__attribute__((address_space(3))) u32*)l, 16, 0, 0);
}

__device__ __forceinline__ void cfence() { asm volatile("" ::: "memory"); }
__device__ __forceinline__ void spin() { __builtin_amdgcn_sched_barrier(0); }

// Stage a 32-row slice of a tile (row stride 256 elems in global) into LDS rows
// [w*32, w*32+32) of a [*][32] buffer, 16B chunks XOR-swizzled by ((row>>1)&3).
// 2 gl_lds per thread.
__device__ __forceinline__ void stage_tile(const u16* __restrict__ src, u16* lds,
                                           int lane, int w, int k0) {
  int sgrow = lane >> 2, sc = lane & 3;
  int r0 = w << 5;
  int ra = r0 + sgrow, rb = ra + 16;
  int kqa = (sc ^ ((ra >> 1) & 3)) << 3;
  int kqb = (sc ^ ((rb >> 1) & 3)) << 3;
  gl_lds16(src + (size_t)ra * 256 + k0 + kqa, lds + r0 * 32);
  gl_lds16(src + (size_t)rb * 256 + k0 + kqb, lds + (r0 + 16) * 32);
}

// 8 waves (512 threads) stage a 128x32 tile: wave w stages rows [w*16, w*16+16),
// 1 gl_lds per thread. Same swizzle as stage_tile.
__device__ __forceinline__ void stage_half(const u16* __restrict__ src, u16* lds,
                                           int lane, int w, int k0) {
  int row = (w << 4) + (lane >> 2);
  int sc = lane & 3;
  int kq = (sc ^ ((row >> 1) & 3)) << 3;
  gl_lds16(src + (size_t)row * 256 + k0 + kq, lds + (w << 4) * 32);
}

__device__ __forceinline__ bf16x8 frag(const u16* lds, int base_row, int m, int quad) {
  int row = base_row + m;
  return *(const bf16x8*)&lds[row * 32 + ((quad ^ ((row >> 1) & 3)) << 3)];
}

__device__ __forceinline__ void mfma16(const u16* As, const u16* Bs, int wi, int wp,
                                       int m, int quad, f32x4 acc[4][4]) {
  bf16x8 af[4], bv[4];
#pragma unroll
  for (int r = 0; r < 4; ++r) af[r] = frag(As, wi + (r << 4), m, quad);
#pragma unroll
  for (int c = 0; c < 4; ++c) bv[c] = frag(Bs, wp + (c << 4), m, quad);
#pragma unroll
  for (int r = 0; r < 4; ++r)
#pragma unroll
    for (int c = 0; c < 4; ++c)
      acc[r][c] = __builtin_amdgcn_mfma_f32_16x16x32_bf16(af[r], bv[c], acc[r][c], 0, 0, 0);
}

// ---- prep: softplus(dt), per-chunk cumsum of dA -----------------------------
__global__ __launch_bounds__(256) void kprep(const float* __restrict__ dt,
                                             const float* __restrict__ A_log,
                                             float* __restrict__ csb,
                                             float* __restrict__ dtvb,
                                             float* __restrict__ cdecb) {
  int blk = blockIdx.x;                 // sj*16 + h
  int h = blk & 15, sj = blk >> 4;
  int s = sj >> 4, j = sj & 15;
  int b = s & 1, dir = s >> 1;
  int i = threadIdx.x;
  int to = tor(dir, j * CK + i);
  __shared__ float sbuf[CK];
  float a = -expf(A_log[h]);
  float raw = dt[((size_t)(b * SL + to)) * (2 * NH) + dir * NH + h];
  float sp = (raw > 20.f) ? raw : log1pf(expf(raw));
  sbuf[i] = sp * a;
  __syncthreads();
  for (int off = 1; off < CK; off <<= 1) {
    float v = (i >= off) ? sbuf[i - off] : 0.f;
    __syncthreads();
    sbuf[i] += v;
    __syncthreads();
  }
  float csv = sbuf[i];
  size_t base = ((size_t)sj * NH + h) * CK;
  csb[base + i] = csv;
  dtvb[base + i] = sp;
  if (i == CK - 1) cdecb[sj * NH + h] = expf(csv);
}

// ---- cast BC -> bf16 B/C with flip applied: [s][t][n], vectorized ------------
__global__ __launch_bounds__(256) void kcast(const float* __restrict__ BC,
                                             u16* __restrict__ Bbf,
                                             u16* __restrict__ Cbf) {
  int blk = blockIdx.x;                 // s*(SL/8) + tg
  int s = blk >> 9, tg = blk & 511;
  int b = s & 1, dir = s >> 1;
  int tid = threadIdx.x;
  int rr = tid >> 6, q = tid & 63;      // 4 rows per iter, 64 threads per row
  int isC = q >> 5, qq = q & 31;
#pragma unroll
  for (int it = 0; it < 2; ++it) {
    int t = tg * 8 + it * 4 + rr;
    int tsrc = tor(dir, t);
    const float* src = BC + ((size_t)(b * SL + tsrc)) * (2 * DS) + q * 8;
    float4 v0 = ((const float4*)src)[0];
    float4 v1 = ((const float4*)src)[1];
    uint4 wv;
    wv.x = (u32)f2bf(v0.x) | ((u32)f2bf(v0.y) << 16);
    wv.y = (u32)f2bf(v0.z) | ((u32)f2bf(v0.w) << 16);
    wv.z = (u32)f2bf(v1.x) | ((u32)f2bf(v1.y) << 16);
    wv.w = (u32)f2bf(v1.z) | ((u32)f2bf(v1.w) << 16);
    u16* dstb = (isC ? Cbf : Bbf) + ((size_t)s * SL + t) * DS + qq * 8;
    *(uint4*)dstb = wv;
  }
}

// ---- transpose B within chunk: BbfT[sj][n][k], one k-slice per block ---------
__global__ __launch_bounds__(256) void ktransB(const u16* __restrict__ Bbf,
                                               u16* __restrict__ BbfT) {
  int blk = blockIdx.x;                 // sj*4 + kslice
  int kslice = blk & 3, sj = blk >> 2;
  int k0 = kslice << 6;
  int s = sj >> 4, j = sj & 15;
  __shared__ u16 T[64 * 264];
  int tid = threadIdx.x;
  const u16* src = Bbf + ((size_t)s * SL + j * CK) * DS;
  u16* dst = BbfT + (size_t)sj * DS * CK;
  int kr = tid >> 2, part = (tid & 3) * 64;
  {
    const uint4* gs = (const uint4*)(src + (size_t)(k0 + kr) * DS + part);
    uint4* tb = (uint4*)&T[kr * 264 + part];
#pragma unroll
    for (int q = 0; q < 8; ++q) tb[q] = gs[q];
  }
  __syncthreads();
  int n = tid;
  u16 col[64];
#pragma unroll
  for (int kq = 0; kq < 64; ++kq) col[kq] = T[kq * 264 + n];
  uint4* ds_ = (uint4*)(dst + (size_t)n * CK + k0);
#pragma unroll
  for (int q = 0; q < 8; ++q) {
    uint4 wv;
    wv.x = (u32)col[q * 8 + 0] | ((u32)col[q * 8 + 1] << 16);
    wv.y = (u32)col[q * 8 + 2] | ((u32)col[q * 8 + 3] << 16);
    wv.z = (u32)col[q * 8 + 4] | ((u32)col[q * 8 + 5] << 16);
    wv.w = (u32)col[q * 8 + 6] | ((u32)col[q * 8 + 7] << 16);
    ds_[q] = wv;
  }
}

// ---- xsT[inst][p][k] = bf16( x[t(k)][h*128+p] * e^{-cs_k} * dt_k ) ----------
// LDS layout [kk][p] (stride 136): vectorized b128 writes (~2-way banks) and
// ~2-way scalar column reads, replacing the old [p][kk] layout whose scalar
// writes were 8-way bank-conflicted on every store.
__global__ __launch_bounds__(256) void kxsT(const float* __restrict__ xg,
                                            const float* __restrict__ csb,
                                            const float* __restrict__ dtvb,
                                            u16* __restrict__ xsT) {
  int inst = blockIdx.x;                // ((s*16+j)*16+h)
  int h = inst & 15, sj = inst >> 4;
  int s = sj >> 4, j = sj & 15;
  int b = s & 1, dir = s >> 1;
  int tid = threadIdx.x;
  __shared__ u16 Ls[32 * 136];          // [kk][p], stride 136
  size_t cbase = ((size_t)sj * NH + h) * CK;
  u16* dst = xsT + (size_t)inst * (128 * 256);
  int kk = tid >> 3;
  int pg = (tid & 7) * 16;
  int p2 = tid >> 1, half = tid & 1;
  for (int k0 = 0; k0 < CK; k0 += 32) {
    int kglob = k0 + kk;
    float sc_ = expf(-csb[cbase + kglob]) * dtvb[cbase + kglob];
    int t = tor(dir, j * CK + kglob);
    const float* src = xg + ((size_t)(b * SL + t)) * DI + h * HD + pg;
    float4 v0 = ((const float4*)src)[0];
    float4 v1 = ((const float4*)src)[1];
    float4 v2 = ((const float4*)src)[2];
    float4 v3 = ((const float4*)src)[3];
    uint4 wa, wb;
    wa.x = (u32)f2bf(v0.x * sc_) | ((u32)f2bf(v0.y * sc_) << 16);
    wa.y = (u32)f2bf(v0.z * sc_) | ((u32)f2bf(v0.w * sc_) << 16);
    wa.z = (u32)f2bf(v1.x * sc_) | ((u32)f2bf(v1.y * sc_) << 16);
    wa.w = (u32)f2bf(v1.z * sc_) | ((u32)f2bf(v1.w * sc_) << 16);
    wb.x = (u32)f2bf(v2.x * sc_) | ((u32)f2bf(v2.y * sc_) << 16);
    wb.y = (u32)f2bf(v2.z * sc_) | ((u32)f2bf(v2.w * sc_) << 16);
    wb.z = (u32)f2bf(v3.x * sc_) | ((u32)f2bf(v3.y * sc_) << 16);
    wb.w = (u32)f2bf(v3.z * sc_) | ((u32)f2bf(v3.w * sc_) << 16);
    __syncthreads();                    // protect Ls from prior-iter readers
    *(uint4*)&Ls[kk * 136 + pg] = wa;
    *(uint4*)&Ls[kk * 136 + pg + 8] = wb;
    __syncthreads();
    u16 col[16];
#pragma unroll
    for (int q = 0; q < 16; ++q) col[q] = Ls[(half * 16 + q) * 136 + p2];
    uint4 w0, w1;
    w0.x = (u32)col[0] | ((u32)col[1] << 16);
    w0.y = (u32)col[2] | ((u32)col[3] << 16);
    w0.z = (u32)col[4] | ((u32)col[5] << 16);
    w0.w = (u32)col[6] | ((u32)col[7] << 16);
    w1.x = (u32)col[8] | ((u32)col[9] << 16);
    w1.y = (u32)col[10] | ((u32)col[11] << 16);
    w1.z = (u32)col[12] | ((u32)col[13] << 16);
    w1.w = (u32)col[14] | ((u32)col[15] << 16);
    *(uint4*)&dst[(size_t)p2 * 256 + k0 + half * 16] = w0;
    *(uint4*)&dst[(size_t)p2 * 256 + k0 + half * 16 + 8] = w1;
  }
}

// ---- CBm[sj][i][k] = bf16( sum_n C[i,n]*B[k,n] ), masked k<=i ---------------
// Counted-vmcnt double-buffered pipeline + XCD-bijective block swizzle.
__global__ __launch_bounds__(256) void kcb(const u16* __restrict__ Cbf,
                                           const u16* __restrict__ Bbf,
                                           u16* __restrict__ CBm) {
  int bid = blockIdx.x;                 // 192 = 8 XCD * 24
  int g = ((bid & 7) * 24) + (bid >> 3);
  int tri = g % 3;                      // 0:(0,0) 1:(1,0) 2:(1,1)
  int sj = g / 3;
  int it0 = tri ? 128 : 0;
  int kt0 = (tri == 2) ? 128 : 0;
  int s = sj >> 4, j = sj & 15;
  __shared__ u16 As[2][128 * 32];
  __shared__ u16 Bs[2][128 * 32];
  int tid = threadIdx.x;
  int w = tid >> 6, lane = tid & 63;
  int wi = (w >> 1) << 6, wp = (w & 1) << 6;
  int m = lane & 15, quad = lane >> 4;
  const u16* Ab = Cbf + ((size_t)s * SL + j * CK + it0) * DS;
  const u16* Bb = Bbf + ((size_t)s * SL + j * CK + kt0) * DS;
  f32x4 zini = {0.f, 0.f, 0.f, 0.f};
  f32x4 acc[4][4];
#pragma unroll
  for (int r = 0; r < 4; ++r)
#pragma unroll
    for (int c = 0; c < 4; ++c) acc[r][c] = zini;
  stage_tile(Ab, As[0], lane, w, 0);
  stage_tile(Bb, Bs[0], lane, w, 0);
  int cur = 0;
  for (int ks = 0; ks < 8; ++ks) {
    if (ks + 1 < 8) {
      int k1 = (ks + 1) << 5;
      stage_tile(Ab, As[cur ^ 1], lane, w, k1);
      stage_tile(Bb, Bs[cur ^ 1], lane, w, k1);
      cfence();
      asm volatile("s_waitcnt vmcnt(4)" ::: "memory");
    } else {
      cfence();
      asm volatile("s_waitcnt vmcnt(0)" ::: "memory");
    }
    spin();
    __builtin_amdgcn_s_barrier();
    spin();
    mfma16(As[cur], Bs[cur], wi, wp, m, quad, acc);
    spin();
    __builtin_amdgcn_s_barrier();
    spin();
    cur ^= 1;
  }
  int diag = (it0 == kt0);
  u16* dst = CBm + ((size_t)sj * CK + it0) * CK + kt0;
#pragma unroll
  for (int r = 0; r < 4; ++r)
#pragma unroll
    for (int rg = 0; rg < 4; ++rg) {
      int irow = wi + (r << 4) + (quad << 2) + rg;
#pragma unroll
      for (int c = 0; c < 4; ++c) {
        int kcol = wp + (c << 4) + m;
        float v = acc[r][c][rg];
        if (diag && kcol > irow) v = 0.f;
        dst[(size_t)irow * CK + kcol] = f2bf(v);
      }
    }
}

// ---- states: prevT[inst][p][n] = e^{cs_last} * sum_k xs[p,k]*B[n,k] ----------
// Merged ntiles + counted-vmcnt double-buffer + XCD-bijective block swizzle.
__global__ __launch_bounds__(512) void kstates(const u16* __restrict__ xsT,
                                               const u16* __restrict__ BbfT,
                                               const float* __restrict__ cdecb,
                                               u16* __restrict__ prevT) {
  int bid = blockIdx.x;                 // 1024 = 8 XCD * 128
  int inst = ((bid & 7) << 7) + (bid >> 3);
  int h = inst & 15, sj = inst >> 4;
  __shared__ u16 As[2][128 * 32];
  __shared__ u16 Bs[2][256 * 32];
  int tid = threadIdx.x;
  int w = tid >> 6, lane = tid & 63;
  int wi = (w >> 2) << 6;               // p tile: 0,64
  int wp = (w & 3) << 6;                // n tile: 0,64,128,192
  int m = lane & 15, quad = lane >> 4;
  const u16* Ab = xsT + (size_t)inst * (128 * 256);        // rows p
  const u16* Bb = BbfT + (size_t)sj * DS * CK;             // rows n (256)
  f32x4 zini = {0.f, 0.f, 0.f, 0.f};
  f32x4 acc[4][4];
#pragma unroll
  for (int r = 0; r < 4; ++r)
#pragma unroll
    for (int c = 0; c < 4; ++c) acc[r][c] = zini;
  stage_half(Ab, As[0], lane, w, 0);
  stage_tile(Bb, Bs[0], lane, w, 0);
  int cur = 0;
  for (int ks = 0; ks < 8; ++ks) {
    if (ks + 1 < 8) {
      int k1 = (ks + 1) << 5;
      stage_half(Ab, As[cur ^ 1], lane, w, k1);
      stage_tile(Bb, Bs[cur ^ 1], lane, w, k1);
      cfence();
      asm volatile("s_waitcnt vmcnt(3)" ::: "memory");
    } else {
      cfence();
      asm volatile("s_waitcnt vmcnt(0)" ::: "memory");
    }
    spin();
    __builtin_amdgcn_s_barrier();
    spin();
    mfma16(As[cur], Bs[cur], wi, wp, m, quad, acc);
    spin();
    __builtin_amdgcn_s_barrier();
    spin();
    cur ^= 1;
  }
  float scale = cdecb[sj * NH + h];
  u16* dst = prevT + (size_t)inst * (128 * 256);
#pragma unroll
  for (int r = 0; r < 4; ++r)
#pragma unroll
    for (int rg = 0; rg < 4; ++rg) {
      int prow = wi + (r << 4) + (quad << 2) + rg;
#pragma unroll
      for (int c = 0; c < 4; ++c) {
        int ncol = wp + (c << 4) + m;
        dst[(size_t)prow * 256 + ncol] = f2bf(acc[r][c][rg] * scale);
      }
    }
}

// ---- inter-chunk recurrence over prevT[s][j][h][p][n] ------------------------
__global__ __launch_bounds__(256) void kscan(u16* __restrict__ prevT,
                                             const float* __restrict__ cdecb) {
  int g = blockIdx.x * 256 + threadIdx.x;
  int n = g & 255;
  int p = (g >> 8) & 127;
  int h = (g >> 15) & 15;
  int s = g >> 19;
  size_t base = (((size_t)(s * 256 + h) * 128) + p) * 256 + n;
  const size_t stride = (size_t)NH * 128 * 256;
  float carry = 0.f;
  for (int j = 0; j < NCH; ++j) {
    size_t idx = base + (size_t)j * stride;
    float sv = bf2f(prevT[idx]);
    prevT[idx] = f2bf(carry);
    carry = carry * cdecb[(s * NCH + j) * NH + h] + sv;
  }
}

// ---- y[i,p] = e^{cs_i} * ( CBm(i,:)·xs(:,p) + C(i,:)·prev(:,p) ) -------------
// Merged itiles + counted-vmcnt double-buffer + XCD-bijective block swizzle.
// Intra steps 4..7 stage only the valid lower A-half (CBm (1,1)); the garbage
// (0,1) quadrant is neither staged nor computed. vmcnt per iter = loads issued
// this iter (wave-uniform), ensuring the prior tile has fully landed.
__global__ __launch_bounds__(512) void ky(const u16* __restrict__ CBm,
                                          const u16* __restrict__ Cbf,
                                          const u16* __restrict__ xsT,
                                          const u16* __restrict__ prevT,
                                          const float* __restrict__ csb,
                                          u16* __restrict__ ytmpb) {
  int bid = blockIdx.x;                 // 1024 = 8 XCD * 128
  int inst = ((bid & 7) << 7) + (bid >> 3);
  int h = inst & 15, sj = inst >> 4;
  int s = sj >> 4, j = sj & 15;
  __shared__ u16 As[2][256 * 32];
  __shared__ u16 Bs[2][128 * 32];
  int tid = threadIdx.x;
  int w = tid >> 6, lane = tid & 63;
  int wi = (w >> 1) << 6;               // i tile: 0,64,128,192
  int wp = (w & 1) << 6;                // p tile: 0,64
  int m = lane & 15, quad = lane >> 4;

  const u16* Ai = CBm + (size_t)sj * CK * CK;              // rows i (256)
  const u16* Ae = Cbf + ((size_t)s * SL + j * CK) * DS;    // rows i (256)
  const u16* Bi = xsT + (size_t)inst * (128 * 256);        // rows p (128)
  const u16* Be = prevT + (size_t)inst * (128 * 256);      // rows p (128)

  f32x4 zini = {0.f, 0.f, 0.f, 0.f};
  f32x4 acc[4][4];
#pragma unroll
  for (int r = 0; r < 4; ++r)
#pragma unroll
    for (int c = 0; c < 4; ++c) acc[r][c] = zini;

  stage_tile(Ai, As[0], lane, w, 0);
  stage_half(Bi, Bs[0], lane, w, 0);
  int cur = 0;
  for (int ks = 0; ks < 16; ++ks) {
    if (ks + 1 < 16) {
      int ksn = ks + 1;
      int intran = ksn < 8;
      int k1 = (intran ? ksn : ksn - 8) << 5;
      if (intran && ksn >= 4) {
        // only A rows 128..255 (CBm quadrant (1,1)) are consumed at these steps
        stage_half(Ai + (size_t)128 * 256, As[cur ^ 1] + 128 * 32, lane, w, k1);
        stage_half(Bi, Bs[cur ^ 1], lane, w, k1);
        cfence();
        asm volatile("s_waitcnt vmcnt(2)" ::: "memory");
      } else {
        stage_tile(intran ? Ai : Ae, As[cur ^ 1], lane, w, k1);
        stage_half(intran ? Bi : Be, Bs[cur ^ 1], lane, w, k1);
        cfence();
        asm volatile("s_waitcnt vmcnt(3)" ::: "memory");
      }
    } else {
      cfence();
      asm volatile("s_waitcnt vmcnt(0)" ::: "memory");
    }
    spin();
    __builtin_amdgcn_s_barrier();
    spin();
    if (ks >= 8 || ks < 4 || wi >= 128)
      mfma16(As[cur], Bs[cur], wi, wp, m, quad, acc);
    spin();
    __builtin_amdgcn_s_barrier();
    spin();
    cur ^= 1;
  }
  const float* csrow = csb + ((size_t)sj * NH + h) * CK;
  u16* yb = ytmpb + ((size_t)s * SL + j * CK) * DI + h * HD;
#pragma unroll
  for (int r = 0; r < 4; ++r)
#pragma unroll
    for (int rg = 0; rg < 4; ++rg) {
      int irow = wi + (r << 4) + (quad << 2) + rg;
      float esc = expf(csrow[irow]);
#pragma unroll
      for (int c = 0; c < 4; ++c) {
        int pcol = wp + (c << 4) + m;
        yb[(size_t)irow * DI + pcol] = f2bf(acc[r][c][rg] * esc);
      }
    }
}

// ---- gate GEMV: gates[b][t][h] = x[b,t,:]·W[h,:] + D[h] ---------------------
__global__ __launch_bounds__(256) void kgate(const float* __restrict__ xg,
                                             const float* __restrict__ Wg,
                                             const float* __restrict__ Dg,
                                             float* __restrict__ gates) {
  int bid = blockIdx.x;                 // NB*SL/16 = 512 blocks
  int b = bid >> 8;
  int t0 = (bid & 255) << 4;            // 16 rows per block
  __shared__ float Wl[16 * 256];        // one 256-col slice of W, f32
  int tid = threadIdx.x;
  int w = tid >> 6, lane = tid & 63;
  int c4 = lane << 2;

  float acc[4][16];
#pragma unroll
  for (int r = 0; r < 4; ++r)
#pragma unroll
    for (int h = 0; h < 16; ++h) acc[r][h] = 0.f;

  for (int i = 0; i < 8; ++i) {
    __syncthreads();                    // protect Wl from prior-iter readers
#pragma unroll
    for (int q = 0; q < 4; ++q) {
      int idx = q * 256 + tid;          // float4 index into the [16][256] slice
      int h = idx >> 6;
      int c = (idx & 63) << 2;
      *(float4*)&Wl[h * 256 + c] = *(const float4*)&Wg[(size_t)h * DI + i * 256 + c];
    }
    __syncthreads();
    float4 Wf[16];
#pragma unroll
    for (int h = 0; h < 16; ++h) Wf[h] = *(const float4*)&Wl[h * 256 + c4];
    // wave w handles rows t0 + w*4 .. +3; W regs reused across the 4 rows
#pragma unroll
    for (int r = 0; r < 4; ++r) {
      int t = t0 + (w << 2) + r;
      float4 xv = *(const float4*)&xg[((size_t)(b * SL + t)) * DI + i * 256 + c4];
#pragma unroll
      for (int h = 0; h < 16; ++h)
        acc[r][h] += xv.x * Wf[h].x + xv.y * Wf[h].y + xv.z * Wf[h].z + xv.w * Wf[h].w;
    }
  }
  // cross-lane reduce (64 lanes each hold a disjoint 128-col partial)
#pragma unroll
  for (int r = 0; r < 4; ++r)
#pragma unroll
    for (int h = 0; h < 16; ++h) {
      float v = acc[r][h];
      v += __shfl_xor(v, 32);
      v += __shfl_xor(v, 16);
      v += __shfl_xor(v, 8);
      v += __shfl_xor(v, 4);
      v += __shfl_xor(v, 2);
      v += __shfl_xor(v, 1);
      acc[r][h] = v;
    }
  if (lane == 0) {
#pragma unroll
    for (int r = 0; r < 4; ++r) {
      int t = t0 + (w << 2) + r;
      float* gdst = gates + ((size_t)(b * SL + t)) * NH;
#pragma unroll
      for (int h = 0; h < 16; ++h) gdst[h] = acc[r][h] + Dg[h];
    }
  }
}

// ---- final stream: out = roll(y_fw) + flip(roll(y_bw)) + x * gate ------------
__device__ __forceinline__ void unpk8(uint4 u, float* o) {
  o[0] = __uint_as_float(u.x << 16); o[1] = __uint_as_float(u.x & 0xffff0000u);
  o[2] = __uint_as_float(u.y << 16); o[3] = __uint_as_float(u.y & 0xffff0000u);
  o[4] = __uint_as_float(u.z << 16); o[5] = __uint_as_float(u.z & 0xffff0000u);
  o[6] = __uint_as_float(u.w << 16); o[7] = __uint_as_float(u.w & 0xffff0000u);
}

// 2048 blocks x 4 rows: no LDS, no barriers, pure coalesced streaming.
__global__ __launch_bounds__(256) void kstream(const float* __restrict__ xg,
                                               const float* __restrict__ gates,
                                               const u16* __restrict__ ytmpb,
                                               float* __restrict__ out) {
  int bid = blockIdx.x;                 // NB*SL/4 = 2048 blocks
  int b = bid >> 10;
  int t0 = (bid & 1023) << 2;           // 4 rows per block
  int tid = threadIdx.x;
  int d0 = tid << 3;
  int h8 = tid >> 4;                    // = d0 >> 7
  const u16* fwbase = ytmpb + (size_t)b * SL * DI + d0;
  const u16* bwbase = ytmpb + (size_t)(2 + b) * SL * DI + d0;
#pragma unroll
  for (int r = 0; r < 4; ++r) {
    int t = t0 + r;
    size_t rowb = ((size_t)(b * SL + t)) * DI + d0;
    float4 x0 = *(const float4*)&xg[rowb];
    float4 x1 = *(const float4*)&xg[rowb + 4];
    float fy[8] = {0.f, 0.f, 0.f, 0.f, 0.f, 0.f, 0.f, 0.f};
    float by[8] = {0.f, 0.f, 0.f, 0.f, 0.f, 0.f, 0.f, 0.f};
    if (t > 0) unpk8(*(const uint4*)(fwbase + (size_t)(t - 1) * DI), fy);
    if (t < SL - 1) unpk8(*(const uint4*)(bwbase + (size_t)(SL - 2 - t) * DI), by);
    float g = gates[((size_t)(b * SL + t)) * NH + h8];
    float4 o0, o1;
    o0.x = fy[0] + by[0] + x0.x * g;
    o0.y = fy[1] + by[1] + x0.y * g;
    o0.z = fy[2] + by[2] + x0.z * g;
    o0.w = fy[3] + by[3] + x0.w * g;
    o1.x = fy[4] + by[4] + x1.x * g;
    o1.y = fy[5] + by[5] + x1.y * g;
    o1.z = fy[6] + by[6] + x1.z * g;
    o1.w = fy[7] + by[7] + x1.w * g;
    *(float4*)&out[rowb] = o0;
    *(float4*)&out[rowb + 4] = o1;
  }
}

extern "C" void kernel_launch(void* const* d_in, const int* in_sizes, int n_in,
                              void* d_out, int out_size, void* d_ws, size_t ws_size,
                              hipStream_t stream) {
  (void)in_sizes; (void)n_in; (void)out_size; (void)ws_size;
  const float* x     = (const float*)d_in[0];
  const float* BC    = (const float*)d_in[1];
  const float* dt    = (const float*)d_in[2];
  const float* A_log = (const float*)d_in[3];
  const float* Dg    = (const float*)d_in[4];
  const float* W     = (const float*)d_in[5];
  float* out = (float*)d_out;

  char* p = (char*)d_ws;
  float* cs    = (float*)p; p += (size_t)NSQ * NCH * NH * CK * 4;        // 1 MB
  float* dtv   = (float*)p; p += (size_t)NSQ * NCH * NH * CK * 4;        // 1 MB
  float* cdec  = (float*)p; p += (size_t)NSQ * NCH * NH * 4;             // 4 KB
  float* gates = (float*)p; p += (size_t)NB * SL * NH * 4;               // 512 KB
  u16* Bbf    = (u16*)p;    p += (size_t)NSQ * SL * DS * 2;              // 8.4 MB
  u16* Cbf    = (u16*)p;    p += (size_t)NSQ * SL * DS * 2;              // 8.4 MB
  u16* BbfT   = (u16*)p;    p += (size_t)NSQ * NCH * DS * CK * 2;        // 8.4 MB
  u16* CBm    = (u16*)p;    p += (size_t)NSQ * NCH * CK * CK * 2;        // 8.4 MB
  u16* xsT    = (u16*)p;    p += (size_t)NSQ * NCH * NH * HD * CK * 2;   // 67 MB
  u16* prevT  = (u16*)p;    p += (size_t)NSQ * NCH * NH * HD * DS * 2;   // 67 MB
  u16* ytmpb  = (u16*)p;    p += (size_t)NSQ * SL * DI * 2;              // 67 MB

  hipLaunchKernelGGL(kgate,   dim3(NB * SL / 16),        dim3(256), 0, stream, x, W, Dg, gates);
  hipLaunchKernelGGL(kprep,   dim3(NSQ * NCH * NH),      dim3(CK),  0, stream, dt, A_log, cs, dtv, cdec);
  hipLaunchKernelGGL(kcast,   dim3(NSQ * SL / 8),        dim3(256), 0, stream, BC, Bbf, Cbf);
  hipLaunchKernelGGL(ktransB, dim3(NSQ * NCH * 4),       dim3(256), 0, stream, Bbf, BbfT);
  hipLaunchKernelGGL(kxsT,    dim3(NSQ * NCH * NH),      dim3(256), 0, stream, x, cs, dtv, xsT);
  hipLaunchKernelGGL(kcb,     dim3(NSQ * NCH * 3),       dim3(256), 0, stream, Cbf, Bbf, CBm);
  hipLaunchKernelGGL(kstates, dim3(NSQ * NCH * NH),      dim3(512), 0, stream, xsT, BbfT, cdec, prevT);
  hipLaunchKernelGGL(kscan,   dim3(NSQ * NH * HD * DS / 256), dim3(256), 0, stream, prevT, cdec);
  hipLaunchKernelGGL(ky,      dim3(NSQ * NCH * NH),      dim3(512), 0, stream, CBm, Cbf, xsT, prevT, cs, ytmpb);
  hipLaunchKernelGGL(kstream, dim3(NB * SL / 4),         dim3(256), 0, stream, x, gates, ytmpb, out);
}

// Round 12
// 347.917 us; speedup vs baseline: 1.0707x; 1.0061x over previous
//
#include <hip/hip_runtime.h>
#include <stdint.h>

#define NB 2
#define SL 4096
#define NH 16
#define HD 128
#define DS 256
#define CK 256
#define NCH 16
#define NSQ 4
#define DI 2048

typedef unsigned short u16;
typedef unsigned int u32;
typedef __attribute__((ext_vector_type(8))) __bf16 bf16x8;
typedef __attribute__((ext_vector_type(4))) float f32x4;

__device__ __forceinline__ int tor(int dir, int t) { return dir ? (SL - 1 - t) : t; }

__device__ __forceinline__ u16 f2bf(float f) {
  u32 u = __float_as_uint(f);
  u = u + 0x7fffu + ((u >> 16) & 1u);   // RNE
  return (u16)(u >> 16);
}
__device__ __forceinline__ float bf2f(u16 s) {
  return __uint_as_float(((u32)s) << 16);
}

__device__ __forceinline__ void gl_lds16(const u16* g, u16* l) {
  __builtin_amdgcn_global_load_lds((const __attribute__((address_space(1))) u32*)g,
                                   (__attribute__((address_space(3))) u32*)l, 16, 0, 0);
}

__device__ __forceinline__ void cfence() { asm volatile("" ::: "memory"); }
__device__ __forceinline__ void spin() { __builtin_amdgcn_sched_barrier(0); }

// Stage a 32-row slice of a tile (row stride 256 elems in global) into LDS rows
// [w*32, w*32+32) of a [*][32] buffer, 16B chunks XOR-swizzled by ((row>>1)&3).
// 2 gl_lds per thread.
__device__ __forceinline__ void stage_tile(const u16* __restrict__ src, u16* lds,
                                           int lane, int w, int k0) {
  int sgrow = lane >> 2, sc = lane & 3;
  int r0 = w << 5;
  int ra = r0 + sgrow, rb = ra + 16;
  int kqa = (sc ^ ((ra >> 1) & 3)) << 3;
  int kqb = (sc ^ ((rb >> 1) & 3)) << 3;
  gl_lds16(src + (size_t)ra * 256 + k0 + kqa, lds + r0 * 32);
  gl_lds16(src + (size_t)rb * 256 + k0 + kqb, lds + (r0 + 16) * 32);
}

// 8 waves (512 threads) stage a 128x32 tile: wave w stages rows [w*16, w*16+16),
// 1 gl_lds per thread. Same swizzle as stage_tile.
__device__ __forceinline__ void stage_half(const u16* __restrict__ src, u16* lds,
                                           int lane, int w, int k0) {
  int row = (w << 4) + (lane >> 2);
  int sc = lane & 3;
  int kq = (sc ^ ((row >> 1) & 3)) << 3;
  gl_lds16(src + (size_t)row * 256 + k0 + kq, lds + (w << 4) * 32);
}

__device__ __forceinline__ bf16x8 frag(const u16* lds, int base_row, int m, int quad) {
  int row = base_row + m;
  return *(const bf16x8*)&lds[row * 32 + ((quad ^ ((row >> 1) & 3)) << 3)];
}

__device__ __forceinline__ void mfma16(const u16* As, const u16* Bs, int wi, int wp,
                                       int m, int quad, f32x4 acc[4][4]) {
  bf16x8 af[4], bv[4];
#pragma unroll
  for (int r = 0; r < 4; ++r) af[r] = frag(As, wi + (r << 4), m, quad);
#pragma unroll
  for (int c = 0; c < 4; ++c) bv[c] = frag(Bs, wp + (c << 4), m, quad);
#pragma unroll
  for (int r = 0; r < 4; ++r)
#pragma unroll
    for (int c = 0; c < 4; ++c)
      acc[r][c] = __builtin_amdgcn_mfma_f32_16x16x32_bf16(af[r], bv[c], acc[r][c], 0, 0, 0);
}

// ---- prep: softplus(dt), per-chunk cumsum of dA -----------------------------
__global__ __launch_bounds__(256) void kprep(const float* __restrict__ dt,
                                             const float* __restrict__ A_log,
                                             float* __restrict__ csb,
                                             float* __restrict__ dtvb,
                                             float* __restrict__ cdecb) {
  int blk = blockIdx.x;                 // sj*16 + h
  int h = blk & 15, sj = blk >> 4;
  int s = sj >> 4, j = sj & 15;
  int b = s & 1, dir = s >> 1;
  int i = threadIdx.x;
  int to = tor(dir, j * CK + i);
  __shared__ float sbuf[CK];
  float a = -expf(A_log[h]);
  float raw = dt[((size_t)(b * SL + to)) * (2 * NH) + dir * NH + h];
  float sp = (raw > 20.f) ? raw : log1pf(expf(raw));
  sbuf[i] = sp * a;
  __syncthreads();
  for (int off = 1; off < CK; off <<= 1) {
    float v = (i >= off) ? sbuf[i - off] : 0.f;
    __syncthreads();
    sbuf[i] += v;
    __syncthreads();
  }
  float csv = sbuf[i];
  size_t base = ((size_t)sj * NH + h) * CK;
  csb[base + i] = csv;
  dtvb[base + i] = sp;
  if (i == CK - 1) cdecb[sj * NH + h] = expf(csv);
}

// ---- cast BC -> bf16 B/C with flip applied: [s][t][n], vectorized ------------
__global__ __launch_bounds__(256) void kcast(const float* __restrict__ BC,
                                             u16* __restrict__ Bbf,
                                             u16* __restrict__ Cbf) {
  int blk = blockIdx.x;                 // s*(SL/8) + tg
  int s = blk >> 9, tg = blk & 511;
  int b = s & 1, dir = s >> 1;
  int tid = threadIdx.x;
  int rr = tid >> 6, q = tid & 63;      // 4 rows per iter, 64 threads per row
  int isC = q >> 5, qq = q & 31;
#pragma unroll
  for (int it = 0; it < 2; ++it) {
    int t = tg * 8 + it * 4 + rr;
    int tsrc = tor(dir, t);
    const float* src = BC + ((size_t)(b * SL + tsrc)) * (2 * DS) + q * 8;
    float4 v0 = ((const float4*)src)[0];
    float4 v1 = ((const float4*)src)[1];
    uint4 wv;
    wv.x = (u32)f2bf(v0.x) | ((u32)f2bf(v0.y) << 16);
    wv.y = (u32)f2bf(v0.z) | ((u32)f2bf(v0.w) << 16);
    wv.z = (u32)f2bf(v1.x) | ((u32)f2bf(v1.y) << 16);
    wv.w = (u32)f2bf(v1.z) | ((u32)f2bf(v1.w) << 16);
    u16* dstb = (isC ? Cbf : Bbf) + ((size_t)s * SL + t) * DS + qq * 8;
    *(uint4*)dstb = wv;
  }
}

// ---- transpose B within chunk: BbfT[sj][n][k], one k-slice per block ---------
__global__ __launch_bounds__(256) void ktransB(const u16* __restrict__ Bbf,
                                               u16* __restrict__ BbfT) {
  int blk = blockIdx.x;                 // sj*4 + kslice
  int kslice = blk & 3, sj = blk >> 2;
  int k0 = kslice << 6;
  int s = sj >> 4, j = sj & 15;
  __shared__ u16 T[64 * 264];
  int tid = threadIdx.x;
  const u16* src = Bbf + ((size_t)s * SL + j * CK) * DS;
  u16* dst = BbfT + (size_t)sj * DS * CK;
  int kr = tid >> 2, part = (tid & 3) * 64;
  {
    const uint4* gs = (const uint4*)(src + (size_t)(k0 + kr) * DS + part);
    uint4* tb = (uint4*)&T[kr * 264 + part];
#pragma unroll
    for (int q = 0; q < 8; ++q) tb[q] = gs[q];
  }
  __syncthreads();
  int n = tid;
  u16 col[64];
#pragma unroll
  for (int kq = 0; kq < 64; ++kq) col[kq] = T[kq * 264 + n];
  uint4* ds_ = (uint4*)(dst + (size_t)n * CK + k0);
#pragma unroll
  for (int q = 0; q < 8; ++q) {
    uint4 wv;
    wv.x = (u32)col[q * 8 + 0] | ((u32)col[q * 8 + 1] << 16);
    wv.y = (u32)col[q * 8 + 2] | ((u32)col[q * 8 + 3] << 16);
    wv.z = (u32)col[q * 8 + 4] | ((u32)col[q * 8 + 5] << 16);
    wv.w = (u32)col[q * 8 + 6] | ((u32)col[q * 8 + 7] << 16);
    ds_[q] = wv;
  }
}

// ---- xsT[inst][p][k] = bf16( x[t(k)][h*128+p] * e^{-cs_k} * dt_k ) ----------
// LDS layout [kk][p] (stride 136). XCD-swizzled inst mapping matches kstates/ky
// so the tile written here stays in the consuming XCD's L2.
__global__ __launch_bounds__(256) void kxsT(const float* __restrict__ xg,
                                            const float* __restrict__ csb,
                                            const float* __restrict__ dtvb,
                                            u16* __restrict__ xsT) {
  int bid = blockIdx.x;                 // 1024 = 8 XCD * 128
  int inst = ((bid & 7) << 7) + (bid >> 3);
  int h = inst & 15, sj = inst >> 4;
  int s = sj >> 4, j = sj & 15;
  int b = s & 1, dir = s >> 1;
  int tid = threadIdx.x;
  __shared__ u16 Ls[32 * 136];          // [kk][p], stride 136
  size_t cbase = ((size_t)sj * NH + h) * CK;
  u16* dst = xsT + (size_t)inst * (128 * 256);
  int kk = tid >> 3;
  int pg = (tid & 7) * 16;
  int p2 = tid >> 1, half = tid & 1;
  for (int k0 = 0; k0 < CK; k0 += 32) {
    int kglob = k0 + kk;
    float sc_ = expf(-csb[cbase + kglob]) * dtvb[cbase + kglob];
    int t = tor(dir, j * CK + kglob);
    const float* src = xg + ((size_t)(b * SL + t)) * DI + h * HD + pg;
    float4 v0 = ((const float4*)src)[0];
    float4 v1 = ((const float4*)src)[1];
    float4 v2 = ((const float4*)src)[2];
    float4 v3 = ((const float4*)src)[3];
    uint4 wa, wb;
    wa.x = (u32)f2bf(v0.x * sc_) | ((u32)f2bf(v0.y * sc_) << 16);
    wa.y = (u32)f2bf(v0.z * sc_) | ((u32)f2bf(v0.w * sc_) << 16);
    wa.z = (u32)f2bf(v1.x * sc_) | ((u32)f2bf(v1.y * sc_) << 16);
    wa.w = (u32)f2bf(v1.z * sc_) | ((u32)f2bf(v1.w * sc_) << 16);
    wb.x = (u32)f2bf(v2.x * sc_) | ((u32)f2bf(v2.y * sc_) << 16);
    wb.y = (u32)f2bf(v2.z * sc_) | ((u32)f2bf(v2.w * sc_) << 16);
    wb.z = (u32)f2bf(v3.x * sc_) | ((u32)f2bf(v3.y * sc_) << 16);
    wb.w = (u32)f2bf(v3.z * sc_) | ((u32)f2bf(v3.w * sc_) << 16);
    __syncthreads();                    // protect Ls from prior-iter readers
    *(uint4*)&Ls[kk * 136 + pg] = wa;
    *(uint4*)&Ls[kk * 136 + pg + 8] = wb;
    __syncthreads();
    u16 col[16];
#pragma unroll
    for (int q = 0; q < 16; ++q) col[q] = Ls[(half * 16 + q) * 136 + p2];
    uint4 w0, w1;
    w0.x = (u32)col[0] | ((u32)col[1] << 16);
    w0.y = (u32)col[2] | ((u32)col[3] << 16);
    w0.z = (u32)col[4] | ((u32)col[5] << 16);
    w0.w = (u32)col[6] | ((u32)col[7] << 16);
    w1.x = (u32)col[8] | ((u32)col[9] << 16);
    w1.y = (u32)col[10] | ((u32)col[11] << 16);
    w1.z = (u32)col[12] | ((u32)col[13] << 16);
    w1.w = (u32)col[14] | ((u32)col[15] << 16);
    *(uint4*)&dst[(size_t)p2 * 256 + k0 + half * 16] = w0;
    *(uint4*)&dst[(size_t)p2 * 256 + k0 + half * 16 + 8] = w1;
  }
}

// ---- CBm[sj][i][k] = bf16( sum_n C[i,n]*B[k,n] ), masked k<=i ---------------
// Counted-vmcnt double-buffered pipeline + XCD-bijective block swizzle.
__global__ __launch_bounds__(256) void kcb(const u16* __restrict__ Cbf,
                                           const u16* __restrict__ Bbf,
                                           u16* __restrict__ CBm) {
  int bid = blockIdx.x;                 // 192 = 8 XCD * 24
  int g = ((bid & 7) * 24) + (bid >> 3);
  int tri = g % 3;                      // 0:(0,0) 1:(1,0) 2:(1,1)
  int sj = g / 3;
  int it0 = tri ? 128 : 0;
  int kt0 = (tri == 2) ? 128 : 0;
  int s = sj >> 4, j = sj & 15;
  __shared__ u16 As[2][128 * 32];
  __shared__ u16 Bs[2][128 * 32];
  int tid = threadIdx.x;
  int w = tid >> 6, lane = tid & 63;
  int wi = (w >> 1) << 6, wp = (w & 1) << 6;
  int m = lane & 15, quad = lane >> 4;
  const u16* Ab = Cbf + ((size_t)s * SL + j * CK + it0) * DS;
  const u16* Bb = Bbf + ((size_t)s * SL + j * CK + kt0) * DS;
  f32x4 zini = {0.f, 0.f, 0.f, 0.f};
  f32x4 acc[4][4];
#pragma unroll
  for (int r = 0; r < 4; ++r)
#pragma unroll
    for (int c = 0; c < 4; ++c) acc[r][c] = zini;
  stage_tile(Ab, As[0], lane, w, 0);
  stage_tile(Bb, Bs[0], lane, w, 0);
  int cur = 0;
  for (int ks = 0; ks < 8; ++ks) {
    if (ks + 1 < 8) {
      int k1 = (ks + 1) << 5;
      stage_tile(Ab, As[cur ^ 1], lane, w, k1);
      stage_tile(Bb, Bs[cur ^ 1], lane, w, k1);
      cfence();
      asm volatile("s_waitcnt vmcnt(4)" ::: "memory");
    } else {
      cfence();
      asm volatile("s_waitcnt vmcnt(0)" ::: "memory");
    }
    spin();
    __builtin_amdgcn_s_barrier();
    spin();
    mfma16(As[cur], Bs[cur], wi, wp, m, quad, acc);
    spin();
    __builtin_amdgcn_s_barrier();
    spin();
    cur ^= 1;
  }
  int diag = (it0 == kt0);
  u16* dst = CBm + ((size_t)sj * CK + it0) * CK + kt0;
#pragma unroll
  for (int r = 0; r < 4; ++r)
#pragma unroll
    for (int rg = 0; rg < 4; ++rg) {
      int irow = wi + (r << 4) + (quad << 2) + rg;
#pragma unroll
      for (int c = 0; c < 4; ++c) {
        int kcol = wp + (c << 4) + m;
        float v = acc[r][c][rg];
        if (diag && kcol > irow) v = 0.f;
        dst[(size_t)irow * CK + kcol] = f2bf(v);
      }
    }
}

// ---- states: prevT[inst][p][n] = e^{cs_last} * sum_k xs[p,k]*B[n,k] ----------
// Merged ntiles + counted-vmcnt double-buffer + XCD-bijective block swizzle.
__global__ __launch_bounds__(512) void kstates(const u16* __restrict__ xsT,
                                               const u16* __restrict__ BbfT,
                                               const float* __restrict__ cdecb,
                                               u16* __restrict__ prevT) {
  int bid = blockIdx.x;                 // 1024 = 8 XCD * 128
  int inst = ((bid & 7) << 7) + (bid >> 3);
  int h = inst & 15, sj = inst >> 4;
  __shared__ u16 As[2][128 * 32];
  __shared__ u16 Bs[2][256 * 32];
  int tid = threadIdx.x;
  int w = tid >> 6, lane = tid & 63;
  int wi = (w >> 2) << 6;               // p tile: 0,64
  int wp = (w & 3) << 6;                // n tile: 0,64,128,192
  int m = lane & 15, quad = lane >> 4;
  const u16* Ab = xsT + (size_t)inst * (128 * 256);        // rows p
  const u16* Bb = BbfT + (size_t)sj * DS * CK;             // rows n (256)
  f32x4 zini = {0.f, 0.f, 0.f, 0.f};
  f32x4 acc[4][4];
#pragma unroll
  for (int r = 0; r < 4; ++r)
#pragma unroll
    for (int c = 0; c < 4; ++c) acc[r][c] = zini;
  stage_half(Ab, As[0], lane, w, 0);
  stage_tile(Bb, Bs[0], lane, w, 0);
  int cur = 0;
  for (int ks = 0; ks < 8; ++ks) {
    if (ks + 1 < 8) {
      int k1 = (ks + 1) << 5;
      stage_half(Ab, As[cur ^ 1], lane, w, k1);
      stage_tile(Bb, Bs[cur ^ 1], lane, w, k1);
      cfence();
      asm volatile("s_waitcnt vmcnt(3)" ::: "memory");
    } else {
      cfence();
      asm volatile("s_waitcnt vmcnt(0)" ::: "memory");
    }
    spin();
    __builtin_amdgcn_s_barrier();
    spin();
    mfma16(As[cur], Bs[cur], wi, wp, m, quad, acc);
    spin();
    __builtin_amdgcn_s_barrier();
    spin();
    cur ^= 1;
  }
  float scale = cdecb[sj * NH + h];
  u16* dst = prevT + (size_t)inst * (128 * 256);
#pragma unroll
  for (int r = 0; r < 4; ++r)
#pragma unroll
    for (int rg = 0; rg < 4; ++rg) {
      int prow = wi + (r << 4) + (quad << 2) + rg;
#pragma unroll
      for (int c = 0; c < 4; ++c) {
        int ncol = wp + (c << 4) + m;
        dst[(size_t)prow * 256 + ncol] = f2bf(acc[r][c][rg] * scale);
      }
    }
}

// ---- inter-chunk recurrence over prevT[s][j][h][p][n] ------------------------
// All 16 chunk loads issued independently up front (one memory latency),
// then the serial carry recurrence runs in registers.
__global__ __launch_bounds__(256) void kscan(u16* __restrict__ prevT,
                                             const float* __restrict__ cdecb) {
  int g = blockIdx.x * 256 + threadIdx.x;
  int n = g & 255;
  int p = (g >> 8) & 127;
  int h = (g >> 15) & 15;
  int s = g >> 19;
  size_t base = (((size_t)(s * 256 + h) * 128) + p) * 256 + n;
  const size_t stride = (size_t)NH * 128 * 256;
  u16 v[NCH];
#pragma unroll
  for (int j = 0; j < NCH; ++j) v[j] = prevT[base + (size_t)j * stride];
  float dec[NCH];
#pragma unroll
  for (int j = 0; j < NCH; ++j) dec[j] = cdecb[(s * NCH + j) * NH + h];
  float carry = 0.f;
#pragma unroll
  for (int j = 0; j < NCH; ++j) {
    float sv = bf2f(v[j]);
    prevT[base + (size_t)j * stride] = f2bf(carry);
    carry = carry * dec[j] + sv;
  }
}

// ---- y[i,p] = e^{cs_i} * ( CBm(i,:)·xs(:,p) + C(i,:)·prev(:,p) ) -------------
// Merged itiles + counted-vmcnt double-buffer + XCD-bijective block swizzle.
// Intra steps 4..7 stage only the valid lower A-half (CBm (1,1)); the garbage
// (0,1) quadrant is neither staged nor computed. vmcnt per iter = loads issued
// this iter (wave-uniform), ensuring the prior tile has fully landed.
__global__ __launch_bounds__(512) void ky(const u16* __restrict__ CBm,
                                          const u16* __restrict__ Cbf,
                                          const u16* __restrict__ xsT,
                                          const u16* __restrict__ prevT,
                                          const float* __restrict__ csb,
                                          u16* __restrict__ ytmpb) {
  int bid = blockIdx.x;                 // 1024 = 8 XCD * 128
  int inst = ((bid & 7) << 7) + (bid >> 3);
  int h = inst & 15, sj = inst >> 4;
  int s = sj >> 4, j = sj & 15;
  __shared__ u16 As[2][256 * 32];
  __shared__ u16 Bs[2][128 * 32];
  int tid = threadIdx.x;
  int w = tid >> 6, lane = tid & 63;
  int wi = (w >> 1) << 6;               // i tile: 0,64,128,192
  int wp = (w & 1) << 6;                // p tile: 0,64
  int m = lane & 15, quad = lane >> 4;

  const u16* Ai = CBm + (size_t)sj * CK * CK;              // rows i (256)
  const u16* Ae = Cbf + ((size_t)s * SL + j * CK) * DS;    // rows i (256)
  const u16* Bi = xsT + (size_t)inst * (128 * 256);        // rows p (128)
  const u16* Be = prevT + (size_t)inst * (128 * 256);      // rows p (128)

  f32x4 zini = {0.f, 0.f, 0.f, 0.f};
  f32x4 acc[4][4];
#pragma unroll
  for (int r = 0; r < 4; ++r)
#pragma unroll
    for (int c = 0; c < 4; ++c) acc[r][c] = zini;

  stage_tile(Ai, As[0], lane, w, 0);
  stage_half(Bi, Bs[0], lane, w, 0);
  int cur = 0;
  for (int ks = 0; ks < 16; ++ks) {
    if (ks + 1 < 16) {
      int ksn = ks + 1;
      int intran = ksn < 8;
      int k1 = (intran ? ksn : ksn - 8) << 5;
      if (intran && ksn >= 4) {
        // only A rows 128..255 (CBm quadrant (1,1)) are consumed at these steps
        stage_half(Ai + (size_t)128 * 256, As[cur ^ 1] + 128 * 32, lane, w, k1);
        stage_half(Bi, Bs[cur ^ 1], lane, w, k1);
        cfence();
        asm volatile("s_waitcnt vmcnt(2)" ::: "memory");
      } else {
        stage_tile(intran ? Ai : Ae, As[cur ^ 1], lane, w, k1);
        stage_half(intran ? Bi : Be, Bs[cur ^ 1], lane, w, k1);
        cfence();
        asm volatile("s_waitcnt vmcnt(3)" ::: "memory");
      }
    } else {
      cfence();
      asm volatile("s_waitcnt vmcnt(0)" ::: "memory");
    }
    spin();
    __builtin_amdgcn_s_barrier();
    spin();
    if (ks >= 8 || ks < 4 || wi >= 128)
      mfma16(As[cur], Bs[cur], wi, wp, m, quad, acc);
    spin();
    __builtin_amdgcn_s_barrier();
    spin();
    cur ^= 1;
  }
  const float* csrow = csb + ((size_t)sj * NH + h) * CK;
  u16* yb = ytmpb + ((size_t)s * SL + j * CK) * DI + h * HD;
#pragma unroll
  for (int r = 0; r < 4; ++r)
#pragma unroll
    for (int rg = 0; rg < 4; ++rg) {
      int irow = wi + (r << 4) + (quad << 2) + rg;
      float esc = expf(csrow[irow]);
#pragma unroll
      for (int c = 0; c < 4; ++c) {
        int pcol = wp + (c << 4) + m;
        yb[(size_t)irow * DI + pcol] = f2bf(acc[r][c][rg] * esc);
      }
    }
}

// ---- gate GEMV: gates[b][t][h] = x[b,t,:]·W[h,:] + D[h] ---------------------
__global__ __launch_bounds__(256) void kgate(const float* __restrict__ xg,
                                             const float* __restrict__ Wg,
                                             const float* __restrict__ Dg,
                                             float* __restrict__ gates) {
  int bid = blockIdx.x;                 // NB*SL/16 = 512 blocks
  int b = bid >> 8;
  int t0 = (bid & 255) << 4;            // 16 rows per block
  __shared__ float Wl[16 * 256];        // one 256-col slice of W, f32
  int tid = threadIdx.x;
  int w = tid >> 6, lane = tid & 63;
  int c4 = lane << 2;

  float acc[4][16];
#pragma unroll
  for (int r = 0; r < 4; ++r)
#pragma unroll
    for (int h = 0; h < 16; ++h) acc[r][h] = 0.f;

  for (int i = 0; i < 8; ++i) {
    __syncthreads();                    // protect Wl from prior-iter readers
#pragma unroll
    for (int q = 0; q < 4; ++q) {
      int idx = q * 256 + tid;          // float4 index into the [16][256] slice
      int h = idx >> 6;
      int c = (idx & 63) << 2;
      *(float4*)&Wl[h * 256 + c] = *(const float4*)&Wg[(size_t)h * DI + i * 256 + c];
    }
    __syncthreads();
    float4 Wf[16];
#pragma unroll
    for (int h = 0; h < 16; ++h) Wf[h] = *(const float4*)&Wl[h * 256 + c4];
    // wave w handles rows t0 + w*4 .. +3; W regs reused across the 4 rows
#pragma unroll
    for (int r = 0; r < 4; ++r) {
      int t = t0 + (w << 2) + r;
      float4 xv = *(const float4*)&xg[((size_t)(b * SL + t)) * DI + i * 256 + c4];
#pragma unroll
      for (int h = 0; h < 16; ++h)
        acc[r][h] += xv.x * Wf[h].x + xv.y * Wf[h].y + xv.z * Wf[h].z + xv.w * Wf[h].w;
    }
  }
  // cross-lane reduce (64 lanes each hold a disjoint 128-col partial)
#pragma unroll
  for (int r = 0; r < 4; ++r)
#pragma unroll
    for (int h = 0; h < 16; ++h) {
      float v = acc[r][h];
      v += __shfl_xor(v, 32);
      v += __shfl_xor(v, 16);
      v += __shfl_xor(v, 8);
      v += __shfl_xor(v, 4);
      v += __shfl_xor(v, 2);
      v += __shfl_xor(v, 1);
      acc[r][h] = v;
    }
  if (lane == 0) {
#pragma unroll
    for (int r = 0; r < 4; ++r) {
      int t = t0 + (w << 2) + r;
      float* gdst = gates + ((size_t)(b * SL + t)) * NH;
#pragma unroll
      for (int h = 0; h < 16; ++h) gdst[h] = acc[r][h] + Dg[h];
    }
  }
}

// ---- final stream: out = roll(y_fw) + flip(roll(y_bw)) + x * gate ------------
__device__ __forceinline__ void unpk8(uint4 u, float* o) {
  o[0] = __uint_as_float(u.x << 16); o[1] = __uint_as_float(u.x & 0xffff0000u);
  o[2] = __uint_as_float(u.y << 16); o[3] = __uint_as_float(u.y & 0xffff0000u);
  o[4] = __uint_as_float(u.z << 16); o[5] = __uint_as_float(u.z & 0xffff0000u);
  o[6] = __uint_as_float(u.w << 16); o[7] = __uint_as_float(u.w & 0xffff0000u);
}

// 2048 blocks x 4 rows: no LDS, no barriers, pure coalesced streaming.
__global__ __launch_bounds__(256) void kstream(const float* __restrict__ xg,
                                               const float* __restrict__ gates,
                                               const u16* __restrict__ ytmpb,
                                               float* __restrict__ out) {
  int bid = blockIdx.x;                 // NB*SL/4 = 2048 blocks
  int b = bid >> 10;
  int t0 = (bid & 1023) << 2;           // 4 rows per block
  int tid = threadIdx.x;
  int d0 = tid << 3;
  int h8 = tid >> 4;                    // = d0 >> 7
  const u16* fwbase = ytmpb + (size_t)b * SL * DI + d0;
  const u16* bwbase = ytmpb + (size_t)(2 + b) * SL * DI + d0;
#pragma unroll
  for (int r = 0; r < 4; ++r) {
    int t = t0 + r;
    size_t rowb = ((size_t)(b * SL + t)) * DI + d0;
    float4 x0 = *(const float4*)&xg[rowb];
    float4 x1 = *(const float4*)&xg[rowb + 4];
    float fy[8] = {0.f, 0.f, 0.f, 0.f, 0.f, 0.f, 0.f, 0.f};
    float by[8] = {0.f, 0.f, 0.f, 0.f, 0.f, 0.f, 0.f, 0.f};
    if (t > 0) unpk8(*(const uint4*)(fwbase + (size_t)(t - 1) * DI), fy);
    if (t < SL - 1) unpk8(*(const uint4*)(bwbase + (size_t)(SL - 2 - t) * DI), by);
    float g = gates[((size_t)(b * SL + t)) * NH + h8];
    float4 o0, o1;
    o0.x = fy[0] + by[0] + x0.x * g;
    o0.y = fy[1] + by[1] + x0.y * g;
    o0.z = fy[2] + by[2] + x0.z * g;
    o0.w = fy[3] + by[3] + x0.w * g;
    o1.x = fy[4] + by[4] + x1.x * g;
    o1.y = fy[5] + by[5] + x1.y * g;
    o1.z = fy[6] + by[6] + x1.z * g;
    o1.w = fy[7] + by[7] + x1.w * g;
    *(float4*)&out[rowb] = o0;
    *(float4*)&out[rowb + 4] = o1;
  }
}

extern "C" void kernel_launch(void* const* d_in, const int* in_sizes, int n_in,
                              void* d_out, int out_size, void* d_ws, size_t ws_size,
                              hipStream_t stream) {
  (void)in_sizes; (void)n_in; (void)out_size; (void)ws_size;
  const float* x     = (const float*)d_in[0];
  const float* BC    = (const float*)d_in[1];
  const float* dt    = (const float*)d_in[2];
  const float* A_log = (const float*)d_in[3];
  const float* Dg    = (const float*)d_in[4];
  const float* W     = (const float*)d_in[5];
  float* out = (float*)d_out;

  char* p = (char*)d_ws;
  float* cs    = (float*)p; p += (size_t)NSQ * NCH * NH * CK * 4;        // 1 MB
  float* dtv   = (float*)p; p += (size_t)NSQ * NCH * NH * CK * 4;        // 1 MB
  float* cdec  = (float*)p; p += (size_t)NSQ * NCH * NH * 4;             // 4 KB
  float* gates = (float*)p; p += (size_t)NB * SL * NH * 4;               // 512 KB
  u16* Bbf    = (u16*)p;    p += (size_t)NSQ * SL * DS * 2;              // 8.4 MB
  u16* Cbf    = (u16*)p;    p += (size_t)NSQ * SL * DS * 2;              // 8.4 MB
  u16* BbfT   = (u16*)p;    p += (size_t)NSQ * NCH * DS * CK * 2;        // 8.4 MB
  u16* CBm    = (u16*)p;    p += (size_t)NSQ * NCH * CK * CK * 2;        // 8.4 MB
  u16* xsT    = (u16*)p;    p += (size_t)NSQ * NCH * NH * HD * CK * 2;   // 67 MB
  u16* prevT  = (u16*)p;    p += (size_t)NSQ * NCH * NH * HD * DS * 2;   // 67 MB
  u16* ytmpb  = (u16*)p;    p += (size_t)NSQ * SL * DI * 2;              // 67 MB

  hipLaunchKernelGGL(kgate,   dim3(NB * SL / 16),        dim3(256), 0, stream, x, W, Dg, gates);
  hipLaunchKernelGGL(kprep,   dim3(NSQ * NCH * NH),      dim3(CK),  0, stream, dt, A_log, cs, dtv, cdec);
  hipLaunchKernelGGL(kcast,   dim3(NSQ * SL / 8),        dim3(256), 0, stream, BC, Bbf, Cbf);
  hipLaunchKernelGGL(ktransB, dim3(NSQ * NCH * 4),       dim3(256), 0, stream, Bbf, BbfT);
  hipLaunchKernelGGL(kcb,     dim3(NSQ * NCH * 3),       dim3(256), 0, stream, Cbf, Bbf, CBm);
  hipLaunchKernelGGL(kxsT,    dim3(NSQ * NCH * NH),      dim3(256), 0, stream, x, cs, dtv, xsT);
  hipLaunchKernelGGL(kstates, dim3(NSQ * NCH * NH),      dim3(512), 0, stream, xsT, BbfT, cdec, prevT);
  hipLaunchKernelGGL(kscan,   dim3(NSQ * NH * HD * DS / 256), dim3(256), 0, stream, prevT, cdec);
  hipLaunchKernelGGL(ky,      dim3(NSQ * NCH * NH),      dim3(512), 0, stream, CBm, Cbf, xsT, prevT, cs, ytmpb);
  hipLaunchKernelGGL(kstream, dim3(NB * SL / 4),         dim3(256), 0, stream, x, gates, ytmpb, out);
}

// Round 14
// 336.904 us; speedup vs baseline: 1.1057x; 1.0327x over previous
//
#include <hip/hip_runtime.h>
#include <stdint.h>

#define NB 2
#define SL 4096
#define NH 16
#define HD 128
#define DS 256
#define CK 256
#define NCH 16
#define NSQ 4
#define DI 2048

typedef unsigned short u16;
typedef unsigned int u32;
typedef __attribute__((ext_vector_type(8))) __bf16 bf16x8;
typedef __attribute__((ext_vector_type(4))) float f32x4;

__device__ __forceinline__ int tor(int dir, int t) { return dir ? (SL - 1 - t) : t; }

__device__ __forceinline__ u16 f2bf(float f) {
  u32 u = __float_as_uint(f);
  u = u + 0x7fffu + ((u >> 16) & 1u);   // RNE
  return (u16)(u >> 16);
}
__device__ __forceinline__ float bf2f(u16 s) {
  return __uint_as_float(((u32)s) << 16);
}

__device__ __forceinline__ void gl_lds16(const u16* g, u16* l) {
  __builtin_amdgcn_global_load_lds((const __attribute__((address_space(1))) u32*)g,
                                   (__attribute__((address_space(3))) u32*)l, 16, 0, 0);
}

__device__ __forceinline__ void cfence() { asm volatile("" ::: "memory"); }
__device__ __forceinline__ void spin() { __builtin_amdgcn_sched_barrier(0); }

// Stage a 32-row slice of a tile (row stride 256 elems in global) into LDS rows
// [w*32, w*32+32) of a [*][32] buffer, 16B chunks XOR-swizzled by ((row>>1)&3).
// 2 gl_lds per thread.
__device__ __forceinline__ void stage_tile(const u16* __restrict__ src, u16* lds,
                                           int lane, int w, int k0) {
  int sgrow = lane >> 2, sc = lane & 3;
  int r0 = w << 5;
  int ra = r0 + sgrow, rb = ra + 16;
  int kqa = (sc ^ ((ra >> 1) & 3)) << 3;
  int kqb = (sc ^ ((rb >> 1) & 3)) << 3;
  gl_lds16(src + (size_t)ra * 256 + k0 + kqa, lds + r0 * 32);
  gl_lds16(src + (size_t)rb * 256 + k0 + kqb, lds + (r0 + 16) * 32);
}

// 8 waves (512 threads) stage a 128x32 tile: wave w stages rows [w*16, w*16+16),
// 1 gl_lds per thread. Same swizzle as stage_tile.
__device__ __forceinline__ void stage_half(const u16* __restrict__ src, u16* lds,
                                           int lane, int w, int k0) {
  int row = (w << 4) + (lane >> 2);
  int sc = lane & 3;
  int kq = (sc ^ ((row >> 1) & 3)) << 3;
  gl_lds16(src + (size_t)row * 256 + k0 + kq, lds + (w << 4) * 32);
}

__device__ __forceinline__ bf16x8 frag(const u16* lds, int base_row, int m, int quad) {
  int row = base_row + m;
  return *(const bf16x8*)&lds[row * 32 + ((quad ^ ((row >> 1) & 3)) << 3)];
}

__device__ __forceinline__ void mfma16(const u16* As, const u16* Bs, int wi, int wp,
                                       int m, int quad, f32x4 acc[4][4]) {
  bf16x8 af[4], bv[4];
#pragma unroll
  for (int r = 0; r < 4; ++r) af[r] = frag(As, wi + (r << 4), m, quad);
#pragma unroll
  for (int c = 0; c < 4; ++c) bv[c] = frag(Bs, wp + (c << 4), m, quad);
#pragma unroll
  for (int r = 0; r < 4; ++r)
#pragma unroll
    for (int c = 0; c < 4; ++c)
      acc[r][c] = __builtin_amdgcn_mfma_f32_16x16x32_bf16(af[r], bv[c], acc[r][c], 0, 0, 0);
}

// ---- prep: softplus(dt), per-chunk cumsum of dA -----------------------------
__global__ __launch_bounds__(256) void kprep(const float* __restrict__ dt,
                                             const float* __restrict__ A_log,
                                             float* __restrict__ csb,
                                             float* __restrict__ dtvb,
                                             float* __restrict__ cdecb) {
  int blk = blockIdx.x;                 // sj*16 + h
  int h = blk & 15, sj = blk >> 4;
  int s = sj >> 4, j = sj & 15;
  int b = s & 1, dir = s >> 1;
  int i = threadIdx.x;
  int to = tor(dir, j * CK + i);
  __shared__ float sbuf[CK];
  float a = -expf(A_log[h]);
  float raw = dt[((size_t)(b * SL + to)) * (2 * NH) + dir * NH + h];
  float sp = (raw > 20.f) ? raw : log1pf(expf(raw));
  sbuf[i] = sp * a;
  __syncthreads();
  for (int off = 1; off < CK; off <<= 1) {
    float v = (i >= off) ? sbuf[i - off] : 0.f;
    __syncthreads();
    sbuf[i] += v;
    __syncthreads();
  }
  float csv = sbuf[i];
  size_t base = ((size_t)sj * NH + h) * CK;
  csb[base + i] = csv;
  dtvb[base + i] = sp;
  if (i == CK - 1) cdecb[sj * NH + h] = expf(csv);
}

// ---- cast BC -> bf16 B/C, fw and bw written from ONE read of each BC row -----
__global__ __launch_bounds__(256) void kcast(const float* __restrict__ BC,
                                             u16* __restrict__ Bbf,
                                             u16* __restrict__ Cbf) {
  int blk = blockIdx.x;                 // b*(SL/8) + tg, 1024 blocks
  int b = blk >> 9, tg = blk & 511;
  int tid = threadIdx.x;
  int rr = tid >> 6, q = tid & 63;      // 4 rows per iter, 64 threads per row
  int isC = q >> 5, qq = q & 31;
#pragma unroll
  for (int it = 0; it < 2; ++it) {
    int tsrc = tg * 8 + it * 4 + rr;    // physical row
    const float* src = BC + ((size_t)(b * SL + tsrc)) * (2 * DS) + q * 8;
    float4 v0 = ((const float4*)src)[0];
    float4 v1 = ((const float4*)src)[1];
    uint4 wv;
    wv.x = (u32)f2bf(v0.x) | ((u32)f2bf(v0.y) << 16);
    wv.y = (u32)f2bf(v0.z) | ((u32)f2bf(v0.w) << 16);
    wv.z = (u32)f2bf(v1.x) | ((u32)f2bf(v1.y) << 16);
    wv.w = (u32)f2bf(v1.z) | ((u32)f2bf(v1.w) << 16);
    u16* base_ = (isC ? Cbf : Bbf);
    *(uint4*)(base_ + ((size_t)b * SL + tsrc) * DS + qq * 8) = wv;                      // fw s=b
    *(uint4*)(base_ + ((size_t)(2 + b) * SL + (SL - 1 - tsrc)) * DS + qq * 8) = wv;     // bw s=2+b
  }
}

// ---- transpose B within chunk: BbfT[sj][n][k], one k-slice per block ---------
__global__ __launch_bounds__(256) void ktransB(const u16* __restrict__ Bbf,
                                               u16* __restrict__ BbfT) {
  int blk = blockIdx.x;                 // sj*4 + kslice
  int kslice = blk & 3, sj = blk >> 2;
  int k0 = kslice << 6;
  int s = sj >> 4, j = sj & 15;
  __shared__ u16 T[64 * 264];
  int tid = threadIdx.x;
  const u16* src = Bbf + ((size_t)s * SL + j * CK) * DS;
  u16* dst = BbfT + (size_t)sj * DS * CK;
  int kr = tid >> 2, part = (tid & 3) * 64;
  {
    const uint4* gs = (const uint4*)(src + (size_t)(k0 + kr) * DS + part);
    uint4* tb = (uint4*)&T[kr * 264 + part];
#pragma unroll
    for (int q = 0; q < 8; ++q) tb[q] = gs[q];
  }
  __syncthreads();
  int n = tid;
  u16 col[64];
#pragma unroll
  for (int kq = 0; kq < 64; ++kq) col[kq] = T[kq * 264 + n];
  uint4* ds_ = (uint4*)(dst + (size_t)n * CK + k0);
#pragma unroll
  for (int q = 0; q < 8; ++q) {
    uint4 wv;
    wv.x = (u32)col[q * 8 + 0] | ((u32)col[q * 8 + 1] << 16);
    wv.y = (u32)col[q * 8 + 2] | ((u32)col[q * 8 + 3] << 16);
    wv.z = (u32)col[q * 8 + 4] | ((u32)col[q * 8 + 5] << 16);
    wv.w = (u32)col[q * 8 + 6] | ((u32)col[q * 8 + 7] << 16);
    ds_[q] = wv;
  }
}

// ---- xsT for BOTH directions from one x read --------------------------------
// Block (b, P, h): fw inst (s=b, j=P) uses x rows of chunk P directly; bw inst
// (s=2+b, j=15-P) uses the SAME rows reversed (col kb = 255-o). One x load
// feeds two scaled bf16 tiles via two LDS transpose buffers.
__global__ __launch_bounds__(256) void kxsT(const float* __restrict__ xg,
                                            const float* __restrict__ csb,
                                            const float* __restrict__ dtvb,
                                            u16* __restrict__ xsT) {
  int bid = blockIdx.x;                 // (b*16 + P)*16 + h, 512 blocks
  int h = bid & 15, bp = bid >> 4;
  int b = bp >> 4, P = bp & 15;
  int sj1 = b * NCH + P;                // fw
  int sj2 = (2 + b) * NCH + (15 - P);   // bw
  int tid = threadIdx.x;
  __shared__ u16 L1[32 * 136];          // [kk][p], stride 136
  __shared__ u16 L2[32 * 136];
  size_t cb1 = ((size_t)sj1 * NH + h) * CK;
  size_t cb2 = ((size_t)sj2 * NH + h) * CK;
  u16* d1 = xsT + (size_t)(sj1 * NH + h) * (128 * 256);
  u16* d2 = xsT + (size_t)(sj2 * NH + h) * (128 * 256);
  int kk = tid >> 3;
  int pg = (tid & 7) * 16;
  int p2 = tid >> 1, half = tid & 1;
  for (int k0 = 0; k0 < CK; k0 += 32) {
    int o = k0 + kk;                    // physical offset within chunk P
    int kb = 255 - o;                   // bw column index
    float s1 = expf(-csb[cb1 + o]) * dtvb[cb1 + o];
    float s2 = expf(-csb[cb2 + kb]) * dtvb[cb2 + kb];
    int t = P * CK + o;
    const float* src = xg + ((size_t)(b * SL + t)) * DI + h * HD + pg;
    float4 v0 = ((const float4*)src)[0];
    float4 v1 = ((const float4*)src)[1];
    float4 v2 = ((const float4*)src)[2];
    float4 v3 = ((const float4*)src)[3];
    float f[16] = {v0.x, v0.y, v0.z, v0.w, v1.x, v1.y, v1.z, v1.w,
                   v2.x, v2.y, v2.z, v2.w, v3.x, v3.y, v3.z, v3.w};
    uint4 a1, b1, a2, b2;
    u32* pa1 = (u32*)&a1; u32* pa2 = (u32*)&a2;
#pragma unroll
    for (int q = 0; q < 4; ++q) {
      pa1[q] = (u32)f2bf(f[q * 2] * s1) | ((u32)f2bf(f[q * 2 + 1] * s1) << 16);
      pa2[q] = (u32)f2bf(f[q * 2] * s2) | ((u32)f2bf(f[q * 2 + 1] * s2) << 16);
    }
    u32* pb1 = (u32*)&b1; u32* pb2 = (u32*)&b2;
#pragma unroll
    for (int q = 0; q < 4; ++q) {
      pb1[q] = (u32)f2bf(f[8 + q * 2] * s1) | ((u32)f2bf(f[8 + q * 2 + 1] * s1) << 16);
      pb2[q] = (u32)f2bf(f[8 + q * 2] * s2) | ((u32)f2bf(f[8 + q * 2 + 1] * s2) << 16);
    }
    __syncthreads();                    // protect L1/L2 from prior-iter readers
    *(uint4*)&L1[kk * 136 + pg] = a1;
    *(uint4*)&L1[kk * 136 + pg + 8] = b1;
    *(uint4*)&L2[(31 - kk) * 136 + pg] = a2;
    *(uint4*)&L2[(31 - kk) * 136 + pg + 8] = b2;
    __syncthreads();
    // fw write at column base k0
    {
      u16 col[16];
#pragma unroll
      for (int q = 0; q < 16; ++q) col[q] = L1[(half * 16 + q) * 136 + p2];
      uint4 w0, w1;
      w0.x = (u32)col[0] | ((u32)col[1] << 16);
      w0.y = (u32)col[2] | ((u32)col[3] << 16);
      w0.z = (u32)col[4] | ((u32)col[5] << 16);
      w0.w = (u32)col[6] | ((u32)col[7] << 16);
      w1.x = (u32)col[8] | ((u32)col[9] << 16);
      w1.y = (u32)col[10] | ((u32)col[11] << 16);
      w1.z = (u32)col[12] | ((u32)col[13] << 16);
      w1.w = (u32)col[14] | ((u32)col[15] << 16);
      *(uint4*)&d1[(size_t)p2 * 256 + k0 + half * 16] = w0;
      *(uint4*)&d1[(size_t)p2 * 256 + k0 + half * 16 + 8] = w1;
    }
    // bw write at column base 224-k0 (L2 row r2=31-kk maps col kb=(224-k0)+r2)
    {
      u16 col[16];
#pragma unroll
      for (int q = 0; q < 16; ++q) col[q] = L2[(half * 16 + q) * 136 + p2];
      uint4 w0, w1;
      w0.x = (u32)col[0] | ((u32)col[1] << 16);
      w0.y = (u32)col[2] | ((u32)col[3] << 16);
      w0.z = (u32)col[4] | ((u32)col[5] << 16);
      w0.w = (u32)col[6] | ((u32)col[7] << 16);
      w1.x = (u32)col[8] | ((u32)col[9] << 16);
      w1.y = (u32)col[10] | ((u32)col[11] << 16);
      w1.z = (u32)col[12] | ((u32)col[13] << 16);
      w1.w = (u32)col[14] | ((u32)col[15] << 16);
      *(uint4*)&d2[(size_t)p2 * 256 + (224 - k0) + half * 16] = w0;
      *(uint4*)&d2[(size_t)p2 * 256 + (224 - k0) + half * 16 + 8] = w1;
    }
  }
}

// ---- CBm[sj][i][k] = bf16( sum_n C[i,n]*B[k,n] ), masked k<=i ---------------
// Counted-vmcnt double-buffered pipeline + XCD-bijective block swizzle.
__global__ __launch_bounds__(256) void kcb(const u16* __restrict__ Cbf,
                                           const u16* __restrict__ Bbf,
                                           u16* __restrict__ CBm) {
  int bid = blockIdx.x;                 // 192 = 8 XCD * 24
  int g = ((bid & 7) * 24) + (bid >> 3);
  int tri = g % 3;                      // 0:(0,0) 1:(1,0) 2:(1,1)
  int sj = g / 3;
  int it0 = tri ? 128 : 0;
  int kt0 = (tri == 2) ? 128 : 0;
  int s = sj >> 4, j = sj & 15;
  __shared__ u16 As[2][128 * 32];
  __shared__ u16 Bs[2][128 * 32];
  int tid = threadIdx.x;
  int w = tid >> 6, lane = tid & 63;
  int wi = (w >> 1) << 6, wp = (w & 1) << 6;
  int m = lane & 15, quad = lane >> 4;
  const u16* Ab = Cbf + ((size_t)s * SL + j * CK + it0) * DS;
  const u16* Bb = Bbf + ((size_t)s * SL + j * CK + kt0) * DS;
  f32x4 zini = {0.f, 0.f, 0.f, 0.f};
  f32x4 acc[4][4];
#pragma unroll
  for (int r = 0; r < 4; ++r)
#pragma unroll
    for (int c = 0; c < 4; ++c) acc[r][c] = zini;
  stage_tile(Ab, As[0], lane, w, 0);
  stage_tile(Bb, Bs[0], lane, w, 0);
  int cur = 0;
  for (int ks = 0; ks < 8; ++ks) {
    if (ks + 1 < 8) {
      int k1 = (ks + 1) << 5;
      stage_tile(Ab, As[cur ^ 1], lane, w, k1);
      stage_tile(Bb, Bs[cur ^ 1], lane, w, k1);
      cfence();
      asm volatile("s_waitcnt vmcnt(4)" ::: "memory");
    } else {
      cfence();
      asm volatile("s_waitcnt vmcnt(0)" ::: "memory");
    }
    spin();
    __builtin_amdgcn_s_barrier();
    spin();
    mfma16(As[cur], Bs[cur], wi, wp, m, quad, acc);
    spin();
    __builtin_amdgcn_s_barrier();
    spin();
    cur ^= 1;
  }
  int diag = (it0 == kt0);
  u16* dst = CBm + ((size_t)sj * CK + it0) * CK + kt0;
#pragma unroll
  for (int r = 0; r < 4; ++r)
#pragma unroll
    for (int rg = 0; rg < 4; ++rg) {
      int irow = wi + (r << 4) + (quad << 2) + rg;
#pragma unroll
      for (int c = 0; c < 4; ++c) {
        int kcol = wp + (c << 4) + m;
        float v = acc[r][c][rg];
        if (diag && kcol > irow) v = 0.f;
        dst[(size_t)irow * CK + kcol] = f2bf(v);
      }
    }
}

// ---- states: prevT[inst][p][n] = e^{cs_last} * sum_k xs[p,k]*B[n,k] ----------
// Merged ntiles + counted-vmcnt double-buffer + XCD-bijective block swizzle.
__global__ __launch_bounds__(512) void kstates(const u16* __restrict__ xsT,
                                               const u16* __restrict__ BbfT,
                                               const float* __restrict__ cdecb,
                                               u16* __restrict__ prevT) {
  int bid = blockIdx.x;                 // 1024 = 8 XCD * 128
  int inst = ((bid & 7) << 7) + (bid >> 3);
  int h = inst & 15, sj = inst >> 4;
  __shared__ u16 As[2][128 * 32];
  __shared__ u16 Bs[2][256 * 32];
  int tid = threadIdx.x;
  int w = tid >> 6, lane = tid & 63;
  int wi = (w >> 2) << 6;               // p tile: 0,64
  int wp = (w & 3) << 6;                // n tile: 0,64,128,192
  int m = lane & 15, quad = lane >> 4;
  const u16* Ab = xsT + (size_t)inst * (128 * 256);        // rows p
  const u16* Bb = BbfT + (size_t)sj * DS * CK;             // rows n (256)
  f32x4 zini = {0.f, 0.f, 0.f, 0.f};
  f32x4 acc[4][4];
#pragma unroll
  for (int r = 0; r < 4; ++r)
#pragma unroll
    for (int c = 0; c < 4; ++c) acc[r][c] = zini;
  stage_half(Ab, As[0], lane, w, 0);
  stage_tile(Bb, Bs[0], lane, w, 0);
  int cur = 0;
  for (int ks = 0; ks < 8; ++ks) {
    if (ks + 1 < 8) {
      int k1 = (ks + 1) << 5;
      stage_half(Ab, As[cur ^ 1], lane, w, k1);
      stage_tile(Bb, Bs[cur ^ 1], lane, w, k1);
      cfence();
      asm volatile("s_waitcnt vmcnt(3)" ::: "memory");
    } else {
      cfence();
      asm volatile("s_waitcnt vmcnt(0)" ::: "memory");
    }
    spin();
    __builtin_amdgcn_s_barrier();
    spin();
    mfma16(As[cur], Bs[cur], wi, wp, m, quad, acc);
    spin();
    __builtin_amdgcn_s_barrier();
    spin();
    cur ^= 1;
  }
  float scale = cdecb[sj * NH + h];
  u16* dst = prevT + (size_t)inst * (128 * 256);
#pragma unroll
  for (int r = 0; r < 4; ++r)
#pragma unroll
    for (int rg = 0; rg < 4; ++rg) {
      int prow = wi + (r << 4) + (quad << 2) + rg;
#pragma unroll
      for (int c = 0; c < 4; ++c) {
        int ncol = wp + (c << 4) + m;
        dst[(size_t)prow * 256 + ncol] = f2bf(acc[r][c][rg] * scale);
      }
    }
}

// ---- inter-chunk recurrence over prevT[s][j][h][p][n] ------------------------
// All 16 chunk loads issued independently up front (one memory latency),
// then the serial carry recurrence runs in registers.
__global__ __launch_bounds__(256) void kscan(u16* __restrict__ prevT,
                                             const float* __restrict__ cdecb) {
  int g = blockIdx.x * 256 + threadIdx.x;
  int n = g & 255;
  int p = (g >> 8) & 127;
  int h = (g >> 15) & 15;
  int s = g >> 19;
  size_t base = (((size_t)(s * 256 + h) * 128) + p) * 256 + n;
  const size_t stride = (size_t)NH * 128 * 256;
  u16 v[NCH];
#pragma unroll
  for (int j = 0; j < NCH; ++j) v[j] = prevT[base + (size_t)j * stride];
  float dec[NCH];
#pragma unroll
  for (int j = 0; j < NCH; ++j) dec[j] = cdecb[(s * NCH + j) * NH + h];
  float carry = 0.f;
#pragma unroll
  for (int j = 0; j < NCH; ++j) {
    float sv = bf2f(v[j]);
    prevT[base + (size_t)j * stride] = f2bf(carry);
    carry = carry * dec[j] + sv;
  }
}

// ---- y[i,p] = e^{cs_i} * ( CBm(i,:)·xs(:,p) + C(i,:)·prev(:,p) ) -------------
// Merged itiles + counted-vmcnt double-buffer + XCD-bijective block swizzle.
// Intra steps 4..7 stage only the valid lower A-half (CBm (1,1)); the garbage
// (0,1) quadrant is neither staged nor computed. vmcnt per iter = loads issued
// this iter (wave-uniform), ensuring the prior tile has fully landed.
__global__ __launch_bounds__(512) void ky(const u16* __restrict__ CBm,
                                          const u16* __restrict__ Cbf,
                                          const u16* __restrict__ xsT,
                                          const u16* __restrict__ prevT,
                                          const float* __restrict__ csb,
                                          u16* __restrict__ ytmpb) {
  int bid = blockIdx.x;                 // 1024 = 8 XCD * 128
  int inst = ((bid & 7) << 7) + (bid >> 3);
  int h = inst & 15, sj = inst >> 4;
  int s = sj >> 4, j = sj & 15;
  __shared__ u16 As[2][256 * 32];
  __shared__ u16 Bs[2][128 * 32];
  int tid = threadIdx.x;
  int w = tid >> 6, lane = tid & 63;
  int wi = (w >> 1) << 6;               // i tile: 0,64,128,192
  int wp = (w & 1) << 6;                // p tile: 0,64
  int m = lane & 15, quad = lane >> 4;

  const u16* Ai = CBm + (size_t)sj * CK * CK;              // rows i (256)
  const u16* Ae = Cbf + ((size_t)s * SL + j * CK) * DS;    // rows i (256)
  const u16* Bi = xsT + (size_t)inst * (128 * 256);        // rows p (128)
  const u16* Be = prevT + (size_t)inst * (128 * 256);      // rows p (128)

  f32x4 zini = {0.f, 0.f, 0.f, 0.f};
  f32x4 acc[4][4];
#pragma unroll
  for (int r = 0; r < 4; ++r)
#pragma unroll
    for (int c = 0; c < 4; ++c) acc[r][c] = zini;

  stage_tile(Ai, As[0], lane, w, 0);
  stage_half(Bi, Bs[0], lane, w, 0);
  int cur = 0;
  for (int ks = 0; ks < 16; ++ks) {
    if (ks + 1 < 16) {
      int ksn = ks + 1;
      int intran = ksn < 8;
      int k1 = (intran ? ksn : ksn - 8) << 5;
      if (intran && ksn >= 4) {
        // only A rows 128..255 (CBm quadrant (1,1)) are consumed at these steps
        stage_half(Ai + (size_t)128 * 256, As[cur ^ 1] + 128 * 32, lane, w, k1);
        stage_half(Bi, Bs[cur ^ 1], lane, w, k1);
        cfence();
        asm volatile("s_waitcnt vmcnt(2)" ::: "memory");
      } else {
        stage_tile(intran ? Ai : Ae, As[cur ^ 1], lane, w, k1);
        stage_half(intran ? Bi : Be, Bs[cur ^ 1], lane, w, k1);
        cfence();
        asm volatile("s_waitcnt vmcnt(3)" ::: "memory");
      }
    } else {
      cfence();
      asm volatile("s_waitcnt vmcnt(0)" ::: "memory");
    }
    spin();
    __builtin_amdgcn_s_barrier();
    spin();
    if (ks >= 8 || ks < 4 || wi >= 128)
      mfma16(As[cur], Bs[cur], wi, wp, m, quad, acc);
    spin();
    __builtin_amdgcn_s_barrier();
    spin();
    cur ^= 1;
  }
  const float* csrow = csb + ((size_t)sj * NH + h) * CK;
  u16* yb = ytmpb + ((size_t)s * SL + j * CK) * DI + h * HD;
#pragma unroll
  for (int r = 0; r < 4; ++r)
#pragma unroll
    for (int rg = 0; rg < 4; ++rg) {
      int irow = wi + (r << 4) + (quad << 2) + rg;
      float esc = expf(csrow[irow]);
#pragma unroll
      for (int c = 0; c < 4; ++c) {
        int pcol = wp + (c << 4) + m;
        yb[(size_t)irow * DI + pcol] = f2bf(acc[r][c][rg] * esc);
      }
    }
}

// ---- gate GEMV: gates[b][t][h] = x[b,t,:]·W[h,:] + D[h] ---------------------
__global__ __launch_bounds__(256) void kgate(const float* __restrict__ xg,
                                             const float* __restrict__ Wg,
                                             const float* __restrict__ Dg,
                                             float* __restrict__ gates) {
  int bid = blockIdx.x;                 // NB*SL/16 = 512 blocks
  int b = bid >> 8;
  int t0 = (bid & 255) << 4;            // 16 rows per block
  __shared__ float Wl[16 * 256];        // one 256-col slice of W, f32
  int tid = threadIdx.x;
  int w = tid >> 6, lane = tid & 63;
  int c4 = lane << 2;

  float acc[4][16];
#pragma unroll
  for (int r = 0; r < 4; ++r)
#pragma unroll
    for (int h = 0; h < 16; ++h) acc[r][h] = 0.f;

  for (int i = 0; i < 8; ++i) {
    __syncthreads();                    // protect Wl from prior-iter readers
#pragma unroll
    for (int q = 0; q < 4; ++q) {
      int idx = q * 256 + tid;          // float4 index into the [16][256] slice
      int h = idx >> 6;
      int c = (idx & 63) << 2;
      *(float4*)&Wl[h * 256 + c] = *(const float4*)&Wg[(size_t)h * DI + i * 256 + c];
    }
    __syncthreads();
    float4 Wf[16];
#pragma unroll
    for (int h = 0; h < 16; ++h) Wf[h] = *(const float4*)&Wl[h * 256 + c4];
    // wave w handles rows t0 + w*4 .. +3; W regs reused across the 4 rows
#pragma unroll
    for (int r = 0; r < 4; ++r) {
      int t = t0 + (w << 2) + r;
      float4 xv = *(const float4*)&xg[((size_t)(b * SL + t)) * DI + i * 256 + c4];
#pragma unroll
      for (int h = 0; h < 16; ++h)
        acc[r][h] += xv.x * Wf[h].x + xv.y * Wf[h].y + xv.z * Wf[h].z + xv.w * Wf[h].w;
    }
  }
  // cross-lane reduce (64 lanes each hold a disjoint 128-col partial)
#pragma unroll
  for (int r = 0; r < 4; ++r)
#pragma unroll
    for (int h = 0; h < 16; ++h) {
      float v = acc[r][h];
      v += __shfl_xor(v, 32);
      v += __shfl_xor(v, 16);
      v += __shfl_xor(v, 8);
      v += __shfl_xor(v, 4);
      v += __shfl_xor(v, 2);
      v += __shfl_xor(v, 1);
      acc[r][h] = v;
    }
  if (lane == 0) {
#pragma unroll
    for (int r = 0; r < 4; ++r) {
      int t = t0 + (w << 2) + r;
      float* gdst = gates + ((size_t)(b * SL + t)) * NH;
#pragma unroll
      for (int h = 0; h < 16; ++h) gdst[h] = acc[r][h] + Dg[h];
    }
  }
}

// ---- final stream: out = roll(y_fw) + flip(roll(y_bw)) + x * gate ------------
__device__ __forceinline__ void unpk8(uint4 u, float* o) {
  o[0] = __uint_as_float(u.x << 16); o[1] = __uint_as_float(u.x & 0xffff0000u);
  o[2] = __uint_as_float(u.y << 16); o[3] = __uint_as_float(u.y & 0xffff0000u);
  o[4] = __uint_as_float(u.z << 16); o[5] = __uint_as_float(u.z & 0xffff0000u);
  o[6] = __uint_as_float(u.w << 16); o[7] = __uint_as_float(u.w & 0xffff0000u);
}

// 2048 blocks x 4 rows: no LDS, no barriers, pure coalesced streaming.
__global__ __launch_bounds__(256) void kstream(const float* __restrict__ xg,
                                               const float* __restrict__ gates,
                                               const u16* __restrict__ ytmpb,
                                               float* __restrict__ out) {
  int bid = blockIdx.x;                 // NB*SL/4 = 2048 blocks
  int b = bid >> 10;
  int t0 = (bid & 1023) << 2;           // 4 rows per block
  int tid = threadIdx.x;
  int d0 = tid << 3;
  int h8 = tid >> 4;                    // = d0 >> 7
  const u16* fwbase = ytmpb + (size_t)b * SL * DI + d0;
  const u16* bwbase = ytmpb + (size_t)(2 + b) * SL * DI + d0;
#pragma unroll
  for (int r = 0; r < 4; ++r) {
    int t = t0 + r;
    size_t rowb = ((size_t)(b * SL + t)) * DI + d0;
    float4 x0 = *(const float4*)&xg[rowb];
    float4 x1 = *(const float4*)&xg[rowb + 4];
    float fy[8] = {0.f, 0.f, 0.f, 0.f, 0.f, 0.f, 0.f, 0.f};
    float by[8] = {0.f, 0.f, 0.f, 0.f, 0.f, 0.f, 0.f, 0.f};
    if (t > 0) unpk8(*(const uint4*)(fwbase + (size_t)(t - 1) * DI), fy);
    if (t < SL - 1) unpk8(*(const uint4*)(bwbase + (size_t)(SL - 2 - t) * DI), by);
    float g = gates[((size_t)(b * SL + t)) * NH + h8];
    float4 o0, o1;
    o0.x = fy[0] + by[0] + x0.x * g;
    o0.y = fy[1] + by[1] + x0.y * g;
    o0.z = fy[2] + by[2] + x0.z * g;
    o0.w = fy[3] + by[3] + x0.w * g;
    o1.x = fy[4] + by[4] + x1.x * g;
    o1.y = fy[5] + by[5] + x1.y * g;
    o1.z = fy[6] + by[6] + x1.z * g;
    o1.w = fy[7] + by[7] + x1.w * g;
    *(float4*)&out[rowb] = o0;
    *(float4*)&out[rowb + 4] = o1;
  }
}

extern "C" void kernel_launch(void* const* d_in, const int* in_sizes, int n_in,
                              void* d_out, int out_size, void* d_ws, size_t ws_size,
                              hipStream_t stream) {
  (void)in_sizes; (void)n_in; (void)out_size; (void)ws_size;
  const float* x     = (const float*)d_in[0];
  const float* BC    = (const float*)d_in[1];
  const float* dt    = (const float*)d_in[2];
  const float* A_log = (const float*)d_in[3];
  const float* Dg    = (const float*)d_in[4];
  const float* W     = (const float*)d_in[5];
  float* out = (float*)d_out;

  char* p = (char*)d_ws;
  float* cs    = (float*)p; p += (size_t)NSQ * NCH * NH * CK * 4;        // 1 MB
  float* dtv   = (float*)p; p += (size_t)NSQ * NCH * NH * CK * 4;        // 1 MB
  float* cdec  = (float*)p; p += (size_t)NSQ * NCH * NH * 4;             // 4 KB
  float* gates = (float*)p; p += (size_t)NB * SL * NH * 4;               // 512 KB
  u16* Bbf    = (u16*)p;    p += (size_t)NSQ * SL * DS * 2;              // 8.4 MB
  u16* Cbf    = (u16*)p;    p += (size_t)NSQ * SL * DS * 2;              // 8.4 MB
  u16* BbfT   = (u16*)p;    p += (size_t)NSQ * NCH * DS * CK * 2;        // 8.4 MB
  u16* CBm    = (u16*)p;    p += (size_t)NSQ * NCH * CK * CK * 2;        // 8.4 MB
  u16* xsT    = (u16*)p;    p += (size_t)NSQ * NCH * NH * HD * CK * 2;   // 67 MB
  u16* prevT  = (u16*)p;    p += (size_t)NSQ * NCH * NH * HD * DS * 2;   // 67 MB
  u16* ytmpb  = (u16*)p;    p += (size_t)NSQ * SL * DI * 2;              // 67 MB

  hipLaunchKernelGGL(kgate,   dim3(NB * SL / 16),        dim3(256), 0, stream, x, W, Dg, gates);
  hipLaunchKernelGGL(kprep,   dim3(NSQ * NCH * NH),      dim3(CK),  0, stream, dt, A_log, cs, dtv, cdec);
  hipLaunchKernelGGL(kcast,   dim3(NB * SL / 8),         dim3(256), 0, stream, BC, Bbf, Cbf);
  hipLaunchKernelGGL(ktransB, dim3(NSQ * NCH * 4),       dim3(256), 0, stream, Bbf, BbfT);
  hipLaunchKernelGGL(kcb,     dim3(NSQ * NCH * 3),       dim3(256), 0, stream, Cbf, Bbf, CBm);
  hipLaunchKernelGGL(kxsT,    dim3(NB * NCH * NH),       dim3(256), 0, stream, x, cs, dtv, xsT);
  hipLaunchKernelGGL(kstates, dim3(NSQ * NCH * NH),      dim3(512), 0, stream, xsT, BbfT, cdec, prevT);
  hipLaunchKernelGGL(kscan,   dim3(NSQ * NH * HD * DS / 256), dim3(256), 0, stream, prevT, cdec);
  hipLaunchKernelGGL(ky,      dim3(NSQ * NCH * NH),      dim3(512), 0, stream, CBm, Cbf, xsT, prevT, cs, ytmpb);
  hipLaunchKernelGGL(kstream, dim3(NB * SL / 4),         dim3(256), 0, stream, x, gates, ytmpb, out);
}